// Round 10
// baseline (1793.891 us; speedup 1.0000x reference)
//
#include <hip/hip_runtime.h>
#include <hip/hip_bf16.h>

typedef __hip_bfloat16 bf16;
typedef short short8 __attribute__((ext_vector_type(8)));
typedef float floatx4 __attribute__((ext_vector_type(4)));

#define BDIM 2048   // E*S
#define HDIM 512
#define LDIM 20
#define CDIM 32
#define LSTR 40     // LDS row stride (bf16) for 32-wide tiles in gemm_tile_k

__device__ __forceinline__ float sigm(float x) { return 1.0f / (1.0f + expf(-x)); }

// ---------------------------------------------------------------------------
// Core 128x128 bf16 MFMA tile: C += A(128xK) @ Bt(128xK)^T. 4 waves in 2x2.
// ---------------------------------------------------------------------------
__device__ __forceinline__ void gemm_tile_k(
    const short* __restrict__ A, int lda,
    const short* __restrict__ Bt, int ldb,
    int K, short* lds, floatx4 (&acc)[4][4], int tid)
{
    short* As = lds;
    short* Bs = lds + 128 * LSTR;
    const int wave = tid >> 6, lane = tid & 63;
    const int wm = wave & 1, wn = wave >> 1;
    const int m16 = lane & 15, quad = lane >> 4;
    const int r0 = tid >> 2;
    const int koff = (tid & 3) * 8;

    for (int k0 = 0; k0 < K; k0 += 32) {
        short8 a0 = *(const short8*)(A + (size_t)r0 * lda + k0 + koff);
        short8 a1 = *(const short8*)(A + (size_t)(r0 + 64) * lda + k0 + koff);
        short8 b0 = *(const short8*)(Bt + (size_t)r0 * ldb + k0 + koff);
        short8 b1 = *(const short8*)(Bt + (size_t)(r0 + 64) * ldb + k0 + koff);
        __syncthreads();
        *(short8*)(As + r0 * LSTR + koff) = a0;
        *(short8*)(As + (r0 + 64) * LSTR + koff) = a1;
        *(short8*)(Bs + r0 * LSTR + koff) = b0;
        *(short8*)(Bs + (r0 + 64) * LSTR + koff) = b1;
        __syncthreads();
        short8 af[4], bfr[4];
#pragma unroll
        for (int i = 0; i < 4; ++i)
            af[i] = *(short8*)(As + (wm * 64 + i * 16 + m16) * LSTR + quad * 8);
#pragma unroll
        for (int j = 0; j < 4; ++j)
            bfr[j] = *(short8*)(Bs + (wn * 64 + j * 16 + m16) * LSTR + quad * 8);
#pragma unroll
        for (int i = 0; i < 4; ++i)
#pragma unroll
            for (int j = 0; j < 4; ++j)
                acc[i][j] = __builtin_amdgcn_mfma_f32_16x16x32_bf16(
                    af[i], bfr[j], acc[i][j], 0, 0, 0);
    }
}

// ---------------------------------------------------------------------------
// Prep kernels
// ---------------------------------------------------------------------------
__global__ __launch_bounds__(256) void k_prep_xb(const float* __restrict__ x,
                                                 bf16* __restrict__ xb)
{
    int i = blockIdx.x * 256 + threadIdx.x;
    xb[i] = (bf16)x[i];
}

__global__ __launch_bounds__(256) void k_transpose_512(const float* __restrict__ src,
                                                       bf16* __restrict__ dst)
{
    __shared__ float tile[32][33];
    int tx = threadIdx.x & 31, ty = threadIdx.x >> 5;
    int k0 = blockIdx.x * 32, n0 = blockIdx.y * 32;
#pragma unroll
    for (int i = 0; i < 32; i += 8)
        tile[ty + i][tx] = src[(size_t)(k0 + ty + i) * 512 + n0 + tx];
    __syncthreads();
#pragma unroll
    for (int i = 0; i < 32; i += 8)
        dst[(size_t)(n0 + ty + i) * 512 + k0 + tx] = (bf16)tile[tx][ty + i];
}

__global__ __launch_bounds__(256) void k_prep_wc(
    const float* __restrict__ w1, const float* __restrict__ w3,
    const float* __restrict__ w5, const float* __restrict__ w7,
    bf16* __restrict__ wt)
{
    int idx = blockIdx.x * 256 + threadIdx.x;
    int g, base;
    if (idx < 65536)       { g = 0; base = 0;      }
    else if (idx < 262144) { g = 1; base = 65536;  }
    else if (idx < 589824) { g = 2; base = 262144; }
    else                   { g = 3; base = 589824; }
    int rel = idx - base;
    int k = 2 * g + 1;
    int ci = rel & 511;
    int t2 = rel >> 9;
    int co = t2 & 127;
    int tap = t2 >> 7;
    const float* w = (g == 0) ? w1 : (g == 1) ? w3 : (g == 2) ? w5 : w7;
    wt[idx] = (bf16)w[((size_t)co * 512 + ci) * k + tap];
}

// [W_mu | W_std] (512x32 each) -> Wh_t[64][512] bf16 (transposed)
__global__ __launch_bounds__(256) void k_prep_wh(const float* __restrict__ Wmu,
                                                 const float* __restrict__ Wstd,
                                                 bf16* __restrict__ Wh_t)
{
    int idx = blockIdx.x * 256 + threadIdx.x;  // 0..32767
    int n = idx >> 9, k = idx & 511;
    float v = (n < 32) ? Wmu[(size_t)k * 32 + n] : Wstd[(size_t)k * 32 + (n - 32)];
    Wh_t[idx] = (bf16)v;
}

// ---------------------------------------------------------------------------
// gx = x @ [Wr_x | Wz_x | Wn_x] + [br|bz|bn]   (M=2048, N=1536, K=512) -> bf16
// ---------------------------------------------------------------------------
__global__ __launch_bounds__(256) void k_gx(
    const bf16* __restrict__ xb, const bf16* __restrict__ Wx_t,
    const float* __restrict__ br, const float* __restrict__ bz,
    const float* __restrict__ bn, bf16* __restrict__ gxb)
{
    __shared__ short lds[2 * 128 * LSTR];
    const int tid = threadIdx.x;
    const int row0 = blockIdx.x * 128, col0 = blockIdx.y * 128;
    floatx4 acc[4][4];
#pragma unroll
    for (int i = 0; i < 4; ++i)
#pragma unroll
        for (int j = 0; j < 4; ++j) acc[i][j] = (floatx4)0.0f;
    gemm_tile_k((const short*)xb + (size_t)row0 * 512, 512,
                (const short*)Wx_t + (size_t)col0 * 512, 512, 512, lds, acc, tid);
    const int wave = tid >> 6, lane = tid & 63;
    const int wm = wave & 1, wn = wave >> 1;
    const int m16 = lane & 15, quad = lane >> 4;
#pragma unroll
    for (int i = 0; i < 4; ++i)
#pragma unroll
        for (int j = 0; j < 4; ++j)
#pragma unroll
            for (int reg = 0; reg < 4; ++reg) {
                int b = row0 + wm * 64 + i * 16 + quad * 4 + reg;
                int n = col0 + wn * 64 + j * 16 + m16;
                float bias = (n < 512) ? br[n] : (n < 1024) ? bz[n - 512] : bn[n - 1024];
                gxb[(size_t)b * 1536 + n] = (bf16)(acc[i][j][reg] + bias);
            }
}

// ---------------------------------------------------------------------------
// GRU step kernel A: pre = h_{t-1} @ [Wr_h|Wz_h] + gx; r-cols -> rh = r*h,
// z-cols -> zbuf. grid (16 rowtiles, 8 coltiles of 1024). Weight slice per
// block is blockIdx-stationary across all 20 launches -> L1/L2-hot.
// K=0 at t=0 (h0 = 0; rh = 0, z = sigm(gxz)).
// ---------------------------------------------------------------------------
__global__ __launch_bounds__(256) void k_rz_s(
    const bf16* __restrict__ hprev, const bf16* __restrict__ Wrz_t,
    const bf16* __restrict__ gxb, bf16* __restrict__ rhb,
    bf16* __restrict__ zbuf, int K)
{
    __shared__ short lds[2 * 128 * LSTR];
    const int tid = threadIdx.x;
    const int row0 = blockIdx.x * 128, col0 = blockIdx.y * 128;
    floatx4 acc[4][4];
#pragma unroll
    for (int i = 0; i < 4; ++i)
#pragma unroll
        for (int j = 0; j < 4; ++j) acc[i][j] = (floatx4)0.0f;
    gemm_tile_k((const short*)hprev + (size_t)row0 * 512, 512,
                (const short*)Wrz_t + (size_t)col0 * 512, 512, K, lds, acc, tid);
    const int wave = tid >> 6, lane = tid & 63;
    const int wm = wave & 1, wn = wave >> 1;
    const int m16 = lane & 15, quad = lane >> 4;
    const bool rside = (col0 < 512);   // block-uniform
#pragma unroll
    for (int i = 0; i < 4; ++i)
#pragma unroll
        for (int j = 0; j < 4; ++j)
#pragma unroll
            for (int reg = 0; reg < 4; ++reg) {
                int b = row0 + wm * 64 + i * 16 + quad * 4 + reg;
                int n = col0 + wn * 64 + j * 16 + m16;
                float v = sigm(acc[i][j][reg] +
                               __bfloat162float(gxb[(size_t)b * 1536 + n]));
                if (rside) {
                    float hval = K ? __bfloat162float(hprev[(size_t)b * 512 + n]) : 0.0f;
                    rhb[(size_t)b * 512 + n] = (bf16)(v * hval);
                } else {
                    zbuf[(size_t)b * 512 + (n - 512)] = (bf16)v;
                }
            }
}

// ---------------------------------------------------------------------------
// GRU step kernel B: n = tanh(rh @ Wn_h + gx_n); h = (1-z)n + z*h.
// h32 is the fp32 master state (guarded by K at t=0 -> no memset needed).
// grid (16 rowtiles, 4 coltiles of 512).
// ---------------------------------------------------------------------------
__global__ __launch_bounds__(256) void k_n_s(
    const bf16* __restrict__ rhb, const bf16* __restrict__ Wn_t,
    const bf16* __restrict__ gxb, const bf16* __restrict__ zbuf,
    float* __restrict__ h32, bf16* __restrict__ hs_t, int K)
{
    __shared__ short lds[2 * 128 * LSTR];
    const int tid = threadIdx.x;
    const int row0 = blockIdx.x * 128, col0 = blockIdx.y * 128;
    floatx4 acc[4][4];
#pragma unroll
    for (int i = 0; i < 4; ++i)
#pragma unroll
        for (int j = 0; j < 4; ++j) acc[i][j] = (floatx4)0.0f;
    gemm_tile_k((const short*)rhb + (size_t)row0 * 512, 512,
                (const short*)Wn_t + (size_t)col0 * 512, 512, K, lds, acc, tid);
    const int wave = tid >> 6, lane = tid & 63;
    const int wm = wave & 1, wn = wave >> 1;
    const int m16 = lane & 15, quad = lane >> 4;
#pragma unroll
    for (int i = 0; i < 4; ++i)
#pragma unroll
        for (int j = 0; j < 4; ++j)
#pragma unroll
            for (int reg = 0; reg < 4; ++reg) {
                int b = row0 + wm * 64 + i * 16 + quad * 4 + reg;
                int n = col0 + wn * 64 + j * 16 + m16;
                size_t idx = (size_t)b * 512 + n;
                float nv = tanhf(acc[i][j][reg] +
                                 __bfloat162float(gxb[(size_t)b * 1536 + 1024 + n]));
                float z = __bfloat162float(zbuf[idx]);
                float hp = K ? h32[idx] : 0.0f;
                float hn = (1.0f - z) * nv + z * hp;
                h32[idx] = hn;
                hs_t[idx] = (bf16)hn;
            }
}

// ---------------------------------------------------------------------------
// Multiscale conv as MFMA GEMM + bias + PReLU -> y bf16 (B, L, 512)
// ---------------------------------------------------------------------------
__global__ __launch_bounds__(256) void k_conv(
    const bf16* __restrict__ hs, const bf16* __restrict__ Wc_t,
    const float* __restrict__ b1, const float* __restrict__ b3,
    const float* __restrict__ b5, const float* __restrict__ b7,
    const float* __restrict__ pa, bf16* __restrict__ y)
{
    __shared__ short lds[2 * 128 * LSTR];
    const int tid = threadIdx.x;
    const int btile = blockIdx.x, g = blockIdx.y, l = blockIdx.z;
    const int row0 = btile * 128;
    const int ktap = 2 * g + 1, p = g;
    const int offs[4] = {0, 65536, 262144, 589824};
    const short* Wg = (const short*)Wc_t + offs[g];
    floatx4 acc[4][4];
#pragma unroll
    for (int i = 0; i < 4; ++i)
#pragma unroll
        for (int j = 0; j < 4; ++j) acc[i][j] = (floatx4)0.0f;
    for (int tap = 0; tap < ktap; ++tap) {
        int li = l + tap - p;
        if (li < 0 || li >= LDIM) continue;
        gemm_tile_k((const short*)hs + (size_t)li * BDIM * HDIM + (size_t)row0 * 512, 512,
                    Wg + (size_t)tap * 128 * 512, 512, 512, lds, acc, tid);
    }
    const float* bp = (g == 0) ? b1 : (g == 1) ? b3 : (g == 2) ? b5 : b7;
    const float a = *pa;
    const int wave = tid >> 6, lane = tid & 63;
    const int wm = wave & 1, wn = wave >> 1;
    const int m16 = lane & 15, quad = lane >> 4;
#pragma unroll
    for (int i = 0; i < 4; ++i)
#pragma unroll
        for (int j = 0; j < 4; ++j)
#pragma unroll
            for (int reg = 0; reg < 4; ++reg) {
                int b = row0 + wm * 64 + i * 16 + quad * 4 + reg;
                int col = wn * 64 + j * 16 + m16;
                float v = acc[i][j][reg] + bp[col];
                v = (v >= 0.0f) ? v : a * v;
                y[((size_t)b * LDIM + l) * 512 + g * 128 + col] = (bf16)v;
            }
}

// ---------------------------------------------------------------------------
// Head as MFMA GEMM: (40960 x 64) = y(40960x512) @ [Wmu|Wstd]^T, fused sample+lp
// ---------------------------------------------------------------------------
__global__ __launch_bounds__(256) void k_head2(
    const bf16* __restrict__ y, const bf16* __restrict__ Wh_t,
    const float* __restrict__ bmu, const float* __restrict__ bstd,
    const float* __restrict__ eps, float* __restrict__ out_comm,
    float* __restrict__ lpsum)
{
    __shared__ short As[128 * LSTR];
    __shared__ short Bs[64 * LSTR];
    const int tid = threadIdx.x;
    const int wave = tid >> 6, lane = tid & 63;
    const int m16 = lane & 15, quad = lane >> 4;
    const int r0 = tid >> 2, koff = (tid & 3) * 8;
    const int row0 = blockIdx.x * 128;
    floatx4 acc[2][4];
#pragma unroll
    for (int i = 0; i < 2; ++i)
#pragma unroll
        for (int j = 0; j < 4; ++j) acc[i][j] = (floatx4)0.0f;
    const short* Ap = (const short*)y + (size_t)row0 * 512;
    const short* Bp = (const short*)Wh_t;
    short8 ga0 = *(const short8*)(Ap + (size_t)r0 * 512 + koff);
    short8 ga1 = *(const short8*)(Ap + (size_t)(r0 + 64) * 512 + koff);
    short8 gb0 = *(const short8*)(Bp + (size_t)r0 * 512 + koff);
    for (int k0 = 0; k0 < 512; k0 += 32) {
        __syncthreads();
        *(short8*)(As + r0 * LSTR + koff) = ga0;
        *(short8*)(As + (r0 + 64) * LSTR + koff) = ga1;
        *(short8*)(Bs + r0 * LSTR + koff) = gb0;
        __syncthreads();
        if (k0 + 32 < 512) {
            ga0 = *(const short8*)(Ap + (size_t)r0 * 512 + k0 + 32 + koff);
            ga1 = *(const short8*)(Ap + (size_t)(r0 + 64) * 512 + k0 + 32 + koff);
            gb0 = *(const short8*)(Bp + (size_t)r0 * 512 + k0 + 32 + koff);
        }
        short8 af[2], bfr[4];
#pragma unroll
        for (int i = 0; i < 2; ++i)
            af[i] = *(short8*)(As + (wave * 32 + i * 16 + m16) * LSTR + quad * 8);
#pragma unroll
        for (int j = 0; j < 4; ++j)
            bfr[j] = *(short8*)(Bs + (j * 16 + m16) * LSTR + quad * 8);
#pragma unroll
        for (int i = 0; i < 2; ++i)
#pragma unroll
            for (int j = 0; j < 4; ++j)
                acc[i][j] = __builtin_amdgcn_mfma_f32_16x16x32_bf16(
                    af[i], bfr[j], acc[i][j], 0, 0, 0);
    }
#pragma unroll
    for (int i = 0; i < 2; ++i)
#pragma unroll
        for (int reg = 0; reg < 4; ++reg) {
            int row = row0 + wave * 32 + i * 16 + quad * 4 + reg;
            float lp = 0.0f;
#pragma unroll
            for (int jj = 0; jj < 2; ++jj) {
                int c = jj * 16 + m16;
                float mu = acc[i][jj][reg] + bmu[c];
                float sraw = acc[i][jj + 2][reg] + bstd[c];
                float sp = (sraw > 20.0f) ? sraw : log1pf(expf(sraw));
                float sd = fminf(fmaxf(sp, 2.0611536e-09f), 7.389056f);
                float e = eps[(size_t)row * 32 + c];
                float comm = fmaf(e, sd, mu);
                float tt = tanhf(comm);
                out_comm[(size_t)row * 32 + c] = tt;
                lp += -0.5f * e * e - logf(sd) - 0.91893853320467274f
                      - logf(1.0f - tt * tt + 1e-6f);
            }
            lp += __shfl_xor(lp, 1, 16);
            lp += __shfl_xor(lp, 2, 16);
            lp += __shfl_xor(lp, 4, 16);
            lp += __shfl_xor(lp, 8, 16);
            if (m16 == 0) lpsum[row] = lp;
        }
}

__global__ __launch_bounds__(256) void k_final(const float* __restrict__ lpsum,
                                               float* __restrict__ out2)
{
    int b = blockIdx.x * 256 + threadIdx.x;
    if (b < BDIM) {
        float s = 0.0f;
#pragma unroll
        for (int i = 0; i < LDIM; ++i) s += lpsum[b * LDIM + i];
        out2[b] = s * (1.0f / (LDIM * CDIM));
    }
}

// ---------------------------------------------------------------------------
extern "C" void kernel_launch(void* const* d_in, const int* in_sizes, int n_in,
                              void* d_out, int out_size, void* d_ws, size_t ws_size,
                              hipStream_t stream)
{
    const float* x    = (const float*)d_in[0];
    const float* Wr   = (const float*)d_in[1];
    const float* br   = (const float*)d_in[2];
    const float* Wz   = (const float*)d_in[3];
    const float* bz   = (const float*)d_in[4];
    const float* Wn   = (const float*)d_in[5];
    const float* bn   = (const float*)d_in[6];
    const float* w1   = (const float*)d_in[7];
    const float* b1   = (const float*)d_in[8];
    const float* w3   = (const float*)d_in[9];
    const float* b3   = (const float*)d_in[10];
    const float* w5   = (const float*)d_in[11];
    const float* b5   = (const float*)d_in[12];
    const float* w7   = (const float*)d_in[13];
    const float* b7   = (const float*)d_in[14];
    const float* pa   = (const float*)d_in[15];
    const float* Wmu  = (const float*)d_in[16];
    const float* bmu  = (const float*)d_in[17];
    const float* Wstd = (const float*)d_in[18];
    const float* bstd = (const float*)d_in[19];
    const float* eps  = (const float*)d_in[20];

    char* cur = (char*)d_ws;
    auto alloc = [&](size_t bytes) -> void* {
        void* r = (void*)cur;
        cur += (bytes + 255) & ~(size_t)255;
        return r;
    };
    const size_t BH = (size_t)BDIM * HDIM;
    bf16*  gxb   = (bf16*)alloc((size_t)BDIM * 1536 * 2);
    bf16*  xb    = (bf16*)alloc(BH * 2);
    bf16*  hs    = (bf16*)alloc(BH * LDIM * 2);
    bf16*  ybuf  = (bf16*)alloc(BH * LDIM * 2);
    bf16*  rhb   = (bf16*)alloc(BH * 2);
    bf16*  zbuf  = (bf16*)alloc(BH * 2);
    float* h32   = (float*)alloc(BH * 4);
    bf16*  Wx_t  = (bf16*)alloc((size_t)1536 * 512 * 2);
    bf16*  Wrz_t = (bf16*)alloc((size_t)1024 * 512 * 2);
    bf16*  Wn_t  = (bf16*)alloc((size_t)512 * 512 * 2);
    bf16*  Wc_t  = (bf16*)alloc((size_t)1048576 * 2);
    bf16*  Wh_t  = (bf16*)alloc((size_t)64 * 512 * 2);
    float* lpsum = (float*)alloc((size_t)BDIM * LDIM * 4);

    k_prep_xb<<<4096, 256, 0, stream>>>(x, xb);
    dim3 tg(16, 16);
    k_transpose_512<<<tg, 256, 0, stream>>>(Wr, Wx_t);          // x-half of Wr
    k_transpose_512<<<tg, 256, 0, stream>>>(Wz, Wx_t + 262144);
    k_transpose_512<<<tg, 256, 0, stream>>>(Wn, Wx_t + 524288);
    k_transpose_512<<<tg, 256, 0, stream>>>(Wr + 262144, Wrz_t);        // h-half
    k_transpose_512<<<tg, 256, 0, stream>>>(Wz + 262144, Wrz_t + 262144);
    k_transpose_512<<<tg, 256, 0, stream>>>(Wn + 262144, Wn_t);
    k_prep_wc<<<4096, 256, 0, stream>>>(w1, w3, w5, w7, Wc_t);
    k_prep_wh<<<128, 256, 0, stream>>>(Wmu, Wstd, Wh_t);

    k_gx<<<dim3(16, 12), 256, 0, stream>>>(xb, Wx_t, br, bz, bn, gxb);

    for (int t = 0; t < LDIM; ++t) {
        const bf16* hprev = (t == 0) ? hs : hs + (size_t)(t - 1) * BH;
        int K = t ? 512 : 0;
        k_rz_s<<<dim3(16, 8), 256, 0, stream>>>(hprev, Wrz_t, gxb, rhb, zbuf, K);
        k_n_s<<<dim3(16, 4), 256, 0, stream>>>(rhb, Wn_t, gxb, zbuf, h32,
                                               hs + (size_t)t * BH, K);
    }

    k_conv<<<dim3(16, 4, 20), 256, 0, stream>>>(hs, Wc_t, b1, b3, b5, b7, pa, ybuf);

    float* out_comm = (float*)d_out;
    float* out_lp   = (float*)d_out + (size_t)BDIM * LDIM * CDIM;
    k_head2<<<320, 256, 0, stream>>>(ybuf, Wh_t, bmu, bstd, eps, out_comm, lpsum);
    k_final<<<8, 256, 0, stream>>>(lpsum, out_lp);
}

// Round 11
// 1434.520 us; speedup vs baseline: 1.2505x; 1.2505x over previous
//
#include <hip/hip_runtime.h>
#include <hip/hip_bf16.h>

typedef __hip_bfloat16 bf16;
typedef short short8 __attribute__((ext_vector_type(8)));
typedef float floatx4 __attribute__((ext_vector_type(4)));

#define BDIM 2048   // E*S
#define HDIM 512
#define LDIM 20
#define CDIM 32
#define LSTR 40     // LDS row stride (bf16) for 32-wide tiles in gemm_tile_k
#define HPAD 520    // LDS row stride for 512-wide state rows (16B-aligned)

__device__ __forceinline__ float sigm(float x) { return 1.0f / (1.0f + expf(-x)); }

// ---------------------------------------------------------------------------
// Core 128x128 bf16 MFMA tile (k_gx / k_conv): C += A(128xK) @ Bt(128xK)^T
// ---------------------------------------------------------------------------
__device__ __forceinline__ void gemm_tile_k(
    const short* __restrict__ A, int lda,
    const short* __restrict__ Bt, int ldb,
    int K, short* lds, floatx4 (&acc)[4][4], int tid)
{
    short* As = lds;
    short* Bs = lds + 128 * LSTR;
    const int wave = tid >> 6, lane = tid & 63;
    const int wm = wave & 1, wn = wave >> 1;
    const int m16 = lane & 15, quad = lane >> 4;
    const int r0 = tid >> 2;
    const int koff = (tid & 3) * 8;

    for (int k0 = 0; k0 < K; k0 += 32) {
        short8 a0 = *(const short8*)(A + (size_t)r0 * lda + k0 + koff);
        short8 a1 = *(const short8*)(A + (size_t)(r0 + 64) * lda + k0 + koff);
        short8 b0 = *(const short8*)(Bt + (size_t)r0 * ldb + k0 + koff);
        short8 b1 = *(const short8*)(Bt + (size_t)(r0 + 64) * ldb + k0 + koff);
        __syncthreads();
        *(short8*)(As + r0 * LSTR + koff) = a0;
        *(short8*)(As + (r0 + 64) * LSTR + koff) = a1;
        *(short8*)(Bs + r0 * LSTR + koff) = b0;
        *(short8*)(Bs + (r0 + 64) * LSTR + koff) = b1;
        __syncthreads();
        short8 af[4], bfr[4];
#pragma unroll
        for (int i = 0; i < 4; ++i)
            af[i] = *(short8*)(As + (wm * 64 + i * 16 + m16) * LSTR + quad * 8);
#pragma unroll
        for (int j = 0; j < 4; ++j)
            bfr[j] = *(short8*)(Bs + (wn * 64 + j * 16 + m16) * LSTR + quad * 8);
#pragma unroll
        for (int i = 0; i < 4; ++i)
#pragma unroll
            for (int j = 0; j < 4; ++j)
                acc[i][j] = __builtin_amdgcn_mfma_f32_16x16x32_bf16(
                    af[i], bfr[j], acc[i][j], 0, 0, 0);
    }
}

// ---------------------------------------------------------------------------
// Prep kernels
// ---------------------------------------------------------------------------
__global__ __launch_bounds__(256) void k_prep_xb(const float* __restrict__ x,
                                                 bf16* __restrict__ xb)
{
    int i = blockIdx.x * 256 + threadIdx.x;
    xb[i] = (bf16)x[i];
}

__global__ __launch_bounds__(256) void k_transpose_512(const float* __restrict__ src,
                                                       bf16* __restrict__ dst)
{
    __shared__ float tile[32][33];
    int tx = threadIdx.x & 31, ty = threadIdx.x >> 5;
    int k0 = blockIdx.x * 32, n0 = blockIdx.y * 32;
#pragma unroll
    for (int i = 0; i < 32; i += 8)
        tile[ty + i][tx] = src[(size_t)(k0 + ty + i) * 512 + n0 + tx];
    __syncthreads();
#pragma unroll
    for (int i = 0; i < 32; i += 8)
        dst[(size_t)(n0 + ty + i) * 512 + k0 + tx] = (bf16)tile[tx][ty + i];
}

// h-part of [Wr|Wz] -> 16-wave 32-col B-fragment stream order:
// WA[(((kc*16 + w)*4 + f)*64 + lane)*8 + j]; f 0..1 = r cols, 2..3 = z cols.
// n = w*32 + (f&1)*16 + (lane&15); k = kc*32 + (lane>>4)*8 + j.
__global__ __launch_bounds__(256) void k_swzA(const float* __restrict__ Wr,
                                              const float* __restrict__ Wz,
                                              bf16* __restrict__ WA)
{
    int idx = blockIdx.x * 256 + threadIdx.x;   // 0..524287
    int j = idx & 7, lane = (idx >> 3) & 63, f = (idx >> 9) & 3,
        w = (idx >> 11) & 15, kc = idx >> 15;
    int n = w * 32 + (f & 1) * 16 + (lane & 15);
    int k = kc * 32 + (lane >> 4) * 8 + j;
    float v = (f < 2) ? Wr[(size_t)(512 + k) * 512 + n]
                      : Wz[(size_t)(512 + k) * 512 + n];
    WA[idx] = (bf16)v;
}

// h-part of Wn: WN[(((kc*16 + w)*2 + f)*64 + lane)*8 + j]
__global__ __launch_bounds__(256) void k_swzN(const float* __restrict__ Wn,
                                              bf16* __restrict__ WN)
{
    int idx = blockIdx.x * 256 + threadIdx.x;   // 0..262143
    int j = idx & 7, lane = (idx >> 3) & 63, f = (idx >> 9) & 1,
        w = (idx >> 10) & 15, kc = idx >> 14;
    int n = w * 32 + f * 16 + (lane & 15);
    int k = kc * 32 + (lane >> 4) * 8 + j;
    WN[idx] = (bf16)Wn[(size_t)(512 + k) * 512 + n];
}

__global__ __launch_bounds__(256) void k_prep_wc(
    const float* __restrict__ w1, const float* __restrict__ w3,
    const float* __restrict__ w5, const float* __restrict__ w7,
    bf16* __restrict__ wt)
{
    int idx = blockIdx.x * 256 + threadIdx.x;
    int g, base;
    if (idx < 65536)       { g = 0; base = 0;      }
    else if (idx < 262144) { g = 1; base = 65536;  }
    else if (idx < 589824) { g = 2; base = 262144; }
    else                   { g = 3; base = 589824; }
    int rel = idx - base;
    int k = 2 * g + 1;
    int ci = rel & 511;
    int t2 = rel >> 9;
    int co = t2 & 127;
    int tap = t2 >> 7;
    const float* w = (g == 0) ? w1 : (g == 1) ? w3 : (g == 2) ? w5 : w7;
    wt[idx] = (bf16)w[((size_t)co * 512 + ci) * k + tap];
}

// [W_mu | W_std] (512x32 each) -> Wh_t[64][512] bf16 (transposed)
__global__ __launch_bounds__(256) void k_prep_wh(const float* __restrict__ Wmu,
                                                 const float* __restrict__ Wstd,
                                                 bf16* __restrict__ Wh_t)
{
    int idx = blockIdx.x * 256 + threadIdx.x;  // 0..32767
    int n = idx >> 9, k = idx & 511;
    float v = (n < 32) ? Wmu[(size_t)k * 32 + n] : Wstd[(size_t)k * 32 + (n - 32)];
    Wh_t[idx] = (bf16)v;
}

// ---------------------------------------------------------------------------
// gx = x @ [Wr_x | Wz_x | Wn_x] + [br|bz|bn]   (M=2048, N=1536, K=512) -> bf16
// ---------------------------------------------------------------------------
__global__ __launch_bounds__(256) void k_gx(
    const bf16* __restrict__ xb, const bf16* __restrict__ Wx_t,
    const float* __restrict__ br, const float* __restrict__ bz,
    const float* __restrict__ bn, bf16* __restrict__ gxb)
{
    __shared__ short lds[2 * 128 * LSTR];
    const int tid = threadIdx.x;
    const int row0 = blockIdx.x * 128, col0 = blockIdx.y * 128;
    floatx4 acc[4][4];
#pragma unroll
    for (int i = 0; i < 4; ++i)
#pragma unroll
        for (int j = 0; j < 4; ++j) acc[i][j] = (floatx4)0.0f;
    gemm_tile_k((const short*)xb + (size_t)row0 * 512, 512,
                (const short*)Wx_t + (size_t)col0 * 512, 512, 512, lds, acc, tid);
    const int wave = tid >> 6, lane = tid & 63;
    const int wm = wave & 1, wn = wave >> 1;
    const int m16 = lane & 15, quad = lane >> 4;
#pragma unroll
    for (int i = 0; i < 4; ++i)
#pragma unroll
        for (int j = 0; j < 4; ++j)
#pragma unroll
            for (int reg = 0; reg < 4; ++reg) {
                int b = row0 + wm * 64 + i * 16 + quad * 4 + reg;
                int n = col0 + wn * 64 + j * 16 + m16;
                float bias = (n < 512) ? br[n] : (n < 1024) ? bz[n - 512] : bn[n - 1024];
                gxb[(size_t)b * 1536 + n] = (bf16)(acc[i][j][reg] + bias);
            }
}

// ---------------------------------------------------------------------------
// Block-local GRU v4b: identical to v4 (round 8, best) EXCEPT the hs store:
// instead of per-thread scattered 2-B stores (partial-line RMW -> L2 churn,
// FETCH 1.6 GB), the h-tile is written from LDS as full-line coalesced
// short8 stores (wave writes contiguous 1 KB runs).
// ---------------------------------------------------------------------------
__global__ __launch_bounds__(1024, 4) void k_gru4(
    const bf16* __restrict__ WA, const bf16* __restrict__ WN,
    const bf16* __restrict__ gxb, bf16* __restrict__ hs)
{
    __shared__ bf16 hb[16 * HPAD];
    __shared__ bf16 rh[16 * HPAD];
    const int tid = threadIdx.x;
    const int wave = tid >> 6, lane = tid & 63;
    const int m16 = lane & 15, quad = lane >> 4;
    const int rowbase = blockIdx.x * 16;
    const int colw = wave * 32;

    // step-invariant gx in registers: this thread's (f,reg) lattice
    float gxr[2][4], gxz[2][4], gxn[2][4];
#pragma unroll
    for (int f = 0; f < 2; ++f)
#pragma unroll
        for (int reg = 0; reg < 4; ++reg) {
            const bf16* gp = gxb + (size_t)(rowbase + quad * 4 + reg) * 1536;
            int col = colw + f * 16 + m16;
            gxr[f][reg] = __bfloat162float(gp[col]);
            gxz[f][reg] = __bfloat162float(gp[512 + col]);
            gxn[f][reg] = __bfloat162float(gp[1024 + col]);
        }

    for (int i = tid; i < 16 * HPAD; i += 1024) hb[i] = (bf16)0.0f;
    __syncthreads();

    const short8* WA8 = (const short8*)WA;  // kc*4096 + wave*256 + f*64 + lane
    const short8* WN8 = (const short8*)WN;  // kc*2048 + wave*128 + f*64 + lane

    float h32[2][4] = {};
    float zst[2][4];

    for (int t = 0; t < LDIM; ++t) {
        // ---------------- phase A: r,z ----------------
        floatx4 accR[2], accZ[2];
#pragma unroll
        for (int f = 0; f < 2; ++f) { accR[f] = (floatx4)0.0f; accZ[f] = (floatx4)0.0f; }
        if (t > 0) {
            const int ba = wave * 256 + lane;
            short8 c0[4], c1[4], c2[4];
#pragma unroll
            for (int f = 0; f < 4; ++f) c0[f] = WA8[ba + f * 64];
#pragma unroll
            for (int f = 0; f < 4; ++f) c1[f] = WA8[4096 + ba + f * 64];
#pragma unroll
            for (int kc = 0; kc < 16; ++kc) {
                if (kc < 14) {
#pragma unroll
                    for (int f = 0; f < 4; ++f)
                        c2[f] = WA8[(size_t)(kc + 2) * 4096 + ba + f * 64];
                }
                short8 a = *(const short8*)((const short*)hb + m16 * HPAD + kc * 32 + quad * 8);
                accR[0] = __builtin_amdgcn_mfma_f32_16x16x32_bf16(a, c0[0], accR[0], 0, 0, 0);
                accR[1] = __builtin_amdgcn_mfma_f32_16x16x32_bf16(a, c0[1], accR[1], 0, 0, 0);
                accZ[0] = __builtin_amdgcn_mfma_f32_16x16x32_bf16(a, c0[2], accZ[0], 0, 0, 0);
                accZ[1] = __builtin_amdgcn_mfma_f32_16x16x32_bf16(a, c0[3], accZ[1], 0, 0, 0);
#pragma unroll
                for (int f = 0; f < 4; ++f) { c0[f] = c1[f]; c1[f] = c2[f]; }
            }
        }
        // epilogue A: r,z; rh -> LDS; z stays in registers
#pragma unroll
        for (int f = 0; f < 2; ++f) {
            int col = colw + f * 16 + m16;
#pragma unroll
            for (int reg = 0; reg < 4; ++reg) {
                int row = quad * 4 + reg;
                float r = sigm(accR[f][reg] + gxr[f][reg]);
                zst[f][reg] = sigm(accZ[f][reg] + gxz[f][reg]);
                rh[row * HPAD + col] = (bf16)(r * h32[f][reg]);
            }
        }
        __syncthreads();
        // ---------------- phase B: n + state update ----------------
        floatx4 accN[2];
#pragma unroll
        for (int f = 0; f < 2; ++f) accN[f] = (floatx4)0.0f;
        if (t > 0) {
            const int bn_ = wave * 128 + lane;
            short8 d0[2], d1[2], d2[2];
#pragma unroll
            for (int f = 0; f < 2; ++f) d0[f] = WN8[bn_ + f * 64];
#pragma unroll
            for (int f = 0; f < 2; ++f) d1[f] = WN8[2048 + bn_ + f * 64];
#pragma unroll
            for (int kc = 0; kc < 16; ++kc) {
                if (kc < 14) {
#pragma unroll
                    for (int f = 0; f < 2; ++f)
                        d2[f] = WN8[(size_t)(kc + 2) * 2048 + bn_ + f * 64];
                }
                short8 a = *(const short8*)((const short*)rh + m16 * HPAD + kc * 32 + quad * 8);
                accN[0] = __builtin_amdgcn_mfma_f32_16x16x32_bf16(a, d0[0], accN[0], 0, 0, 0);
                accN[1] = __builtin_amdgcn_mfma_f32_16x16x32_bf16(a, d0[1], accN[1], 0, 0, 0);
#pragma unroll
                for (int f = 0; f < 2; ++f) { d0[f] = d1[f]; d1[f] = d2[f]; }
            }
        }
#pragma unroll
        for (int f = 0; f < 2; ++f) {
            int col = colw + f * 16 + m16;
#pragma unroll
            for (int reg = 0; reg < 4; ++reg) {
                int row = quad * 4 + reg;
                float nv = tanhf(accN[f][reg] + gxn[f][reg]);
                float z = zst[f][reg];
                float hn = (1.0f - z) * nv + z * h32[f][reg];
                h32[f][reg] = hn;
                hb[row * HPAD + col] = (bf16)hn;
            }
        }
        __syncthreads();
        // coalesced full-line hs write: 1024 threads x short8 = 16x512 tile,
        // wave-contiguous 1 KB runs -> no partial-line RMW, no L2 churn.
        {
            int row = tid >> 6;          // 0..15
            int c8 = (tid & 63) * 8;     // 0..504 step 8
            short8 v = *(const short8*)((const short*)hb + row * HPAD + c8);
            *(short8*)((short*)hs + ((size_t)t * BDIM + rowbase + row) * 512 + c8) = v;
        }
        __syncthreads();
    }
}

// ---------------------------------------------------------------------------
// Multiscale conv as MFMA GEMM + bias + PReLU -> y bf16 (B, L, 512)
// ---------------------------------------------------------------------------
__global__ __launch_bounds__(256) void k_conv(
    const bf16* __restrict__ hs, const bf16* __restrict__ Wc_t,
    const float* __restrict__ b1, const float* __restrict__ b3,
    const float* __restrict__ b5, const float* __restrict__ b7,
    const float* __restrict__ pa, bf16* __restrict__ y)
{
    __shared__ short lds[2 * 128 * LSTR];
    const int tid = threadIdx.x;
    const int btile = blockIdx.x, g = blockIdx.y, l = blockIdx.z;
    const int row0 = btile * 128;
    const int ktap = 2 * g + 1, p = g;
    const int offs[4] = {0, 65536, 262144, 589824};
    const short* Wg = (const short*)Wc_t + offs[g];
    floatx4 acc[4][4];
#pragma unroll
    for (int i = 0; i < 4; ++i)
#pragma unroll
        for (int j = 0; j < 4; ++j) acc[i][j] = (floatx4)0.0f;
    for (int tap = 0; tap < ktap; ++tap) {
        int li = l + tap - p;
        if (li < 0 || li >= LDIM) continue;
        gemm_tile_k((const short*)hs + (size_t)li * BDIM * HDIM + (size_t)row0 * 512, 512,
                    Wg + (size_t)tap * 128 * 512, 512, 512, lds, acc, tid);
    }
    const float* bp = (g == 0) ? b1 : (g == 1) ? b3 : (g == 2) ? b5 : b7;
    const float a = *pa;
    const int wave = tid >> 6, lane = tid & 63;
    const int wm = wave & 1, wn = wave >> 1;
    const int m16 = lane & 15, quad = lane >> 4;
#pragma unroll
    for (int i = 0; i < 4; ++i)
#pragma unroll
        for (int j = 0; j < 4; ++j)
#pragma unroll
            for (int reg = 0; reg < 4; ++reg) {
                int b = row0 + wm * 64 + i * 16 + quad * 4 + reg;
                int col = wn * 64 + j * 16 + m16;
                float v = acc[i][j][reg] + bp[col];
                v = (v >= 0.0f) ? v : a * v;
                y[((size_t)b * LDIM + l) * 512 + g * 128 + col] = (bf16)v;
            }
}

// ---------------------------------------------------------------------------
// Head as MFMA GEMM: (40960 x 64) = y(40960x512) @ [Wmu|Wstd]^T, fused sample+lp
// ---------------------------------------------------------------------------
__global__ __launch_bounds__(256) void k_head2(
    const bf16* __restrict__ y, const bf16* __restrict__ Wh_t,
    const float* __restrict__ bmu, const float* __restrict__ bstd,
    const float* __restrict__ eps, float* __restrict__ out_comm,
    float* __restrict__ lpsum)
{
    __shared__ short As[128 * LSTR];
    __shared__ short Bs[64 * LSTR];
    const int tid = threadIdx.x;
    const int wave = tid >> 6, lane = tid & 63;
    const int m16 = lane & 15, quad = lane >> 4;
    const int r0 = tid >> 2, koff = (tid & 3) * 8;
    const int row0 = blockIdx.x * 128;
    floatx4 acc[2][4];
#pragma unroll
    for (int i = 0; i < 2; ++i)
#pragma unroll
        for (int j = 0; j < 4; ++j) acc[i][j] = (floatx4)0.0f;
    const short* Ap = (const short*)y + (size_t)row0 * 512;
    const short* Bp = (const short*)Wh_t;
    short8 ga0 = *(const short8*)(Ap + (size_t)r0 * 512 + koff);
    short8 ga1 = *(const short8*)(Ap + (size_t)(r0 + 64) * 512 + koff);
    short8 gb0 = *(const short8*)(Bp + (size_t)r0 * 512 + koff);
    for (int k0 = 0; k0 < 512; k0 += 32) {
        __syncthreads();
        *(short8*)(As + r0 * LSTR + koff) = ga0;
        *(short8*)(As + (r0 + 64) * LSTR + koff) = ga1;
        *(short8*)(Bs + r0 * LSTR + koff) = gb0;
        __syncthreads();
        if (k0 + 32 < 512) {
            ga0 = *(const short8*)(Ap + (size_t)r0 * 512 + k0 + 32 + koff);
            ga1 = *(const short8*)(Ap + (size_t)(r0 + 64) * 512 + k0 + 32 + koff);
            gb0 = *(const short8*)(Bp + (size_t)r0 * 512 + k0 + 32 + koff);
        }
        short8 af[2], bfr[4];
#pragma unroll
        for (int i = 0; i < 2; ++i)
            af[i] = *(short8*)(As + (wave * 32 + i * 16 + m16) * LSTR + quad * 8);
#pragma unroll
        for (int j = 0; j < 4; ++j)
            bfr[j] = *(short8*)(Bs + (j * 16 + m16) * LSTR + quad * 8);
#pragma unroll
        for (int i = 0; i < 2; ++i)
#pragma unroll
            for (int j = 0; j < 4; ++j)
                acc[i][j] = __builtin_amdgcn_mfma_f32_16x16x32_bf16(
                    af[i], bfr[j], acc[i][j], 0, 0, 0);
    }
#pragma unroll
    for (int i = 0; i < 2; ++i)
#pragma unroll
        for (int reg = 0; reg < 4; ++reg) {
            int row = row0 + wave * 32 + i * 16 + quad * 4 + reg;
            float lp = 0.0f;
#pragma unroll
            for (int jj = 0; jj < 2; ++jj) {
                int c = jj * 16 + m16;
                float mu = acc[i][jj][reg] + bmu[c];
                float sraw = acc[i][jj + 2][reg] + bstd[c];
                float sp = (sraw > 20.0f) ? sraw : log1pf(expf(sraw));
                float sd = fminf(fmaxf(sp, 2.0611536e-09f), 7.389056f);
                float e = eps[(size_t)row * 32 + c];
                float comm = fmaf(e, sd, mu);
                float tt = tanhf(comm);
                out_comm[(size_t)row * 32 + c] = tt;
                lp += -0.5f * e * e - logf(sd) - 0.91893853320467274f
                      - logf(1.0f - tt * tt + 1e-6f);
            }
            lp += __shfl_xor(lp, 1, 16);
            lp += __shfl_xor(lp, 2, 16);
            lp += __shfl_xor(lp, 4, 16);
            lp += __shfl_xor(lp, 8, 16);
            if (m16 == 0) lpsum[row] = lp;
        }
}

__global__ __launch_bounds__(256) void k_final(const float* __restrict__ lpsum,
                                               float* __restrict__ out2)
{
    int b = blockIdx.x * 256 + threadIdx.x;
    if (b < BDIM) {
        float s = 0.0f;
#pragma unroll
        for (int i = 0; i < LDIM; ++i) s += lpsum[b * LDIM + i];
        out2[b] = s * (1.0f / (LDIM * CDIM));
    }
}

// ---------------------------------------------------------------------------
extern "C" void kernel_launch(void* const* d_in, const int* in_sizes, int n_in,
                              void* d_out, int out_size, void* d_ws, size_t ws_size,
                              hipStream_t stream)
{
    const float* x    = (const float*)d_in[0];
    const float* Wr   = (const float*)d_in[1];
    const float* br   = (const float*)d_in[2];
    const float* Wz   = (const float*)d_in[3];
    const float* bz   = (const float*)d_in[4];
    const float* Wn   = (const float*)d_in[5];
    const float* bn   = (const float*)d_in[6];
    const float* w1   = (const float*)d_in[7];
    const float* b1   = (const float*)d_in[8];
    const float* w3   = (const float*)d_in[9];
    const float* b3   = (const float*)d_in[10];
    const float* w5   = (const float*)d_in[11];
    const float* b5   = (const float*)d_in[12];
    const float* w7   = (const float*)d_in[13];
    const float* b7   = (const float*)d_in[14];
    const float* pa   = (const float*)d_in[15];
    const float* Wmu  = (const float*)d_in[16];
    const float* bmu  = (const float*)d_in[17];
    const float* Wstd = (const float*)d_in[18];
    const float* bstd = (const float*)d_in[19];
    const float* eps  = (const float*)d_in[20];

    char* cur = (char*)d_ws;
    auto alloc = [&](size_t bytes) -> void* {
        void* r = (void*)cur;
        cur += (bytes + 255) & ~(size_t)255;
        return r;
    };
    const size_t BH = (size_t)BDIM * HDIM;
    bf16*  gxb   = (bf16*)alloc((size_t)BDIM * 1536 * 2);
    bf16*  xb    = (bf16*)alloc(BH * 2);
    bf16*  hs    = (bf16*)alloc(BH * LDIM * 2);
    bf16*  ybuf  = (bf16*)alloc(BH * LDIM * 2);
    bf16*  Wx_t  = (bf16*)alloc((size_t)1536 * 512 * 2);
    bf16*  WA    = (bf16*)alloc((size_t)524288 * 2);
    bf16*  WN    = (bf16*)alloc((size_t)262144 * 2);
    bf16*  Wc_t  = (bf16*)alloc((size_t)1048576 * 2);
    bf16*  Wh_t  = (bf16*)alloc((size_t)64 * 512 * 2);
    float* lpsum = (float*)alloc((size_t)BDIM * LDIM * 4);

    k_prep_xb<<<4096, 256, 0, stream>>>(x, xb);
    dim3 tg(16, 16);
    k_transpose_512<<<tg, 256, 0, stream>>>(Wr, Wx_t);         // x-half of Wr
    k_transpose_512<<<tg, 256, 0, stream>>>(Wz, Wx_t + 262144);
    k_transpose_512<<<tg, 256, 0, stream>>>(Wn, Wx_t + 524288);
    k_swzA<<<2048, 256, 0, stream>>>(Wr, Wz, WA);
    k_swzN<<<1024, 256, 0, stream>>>(Wn, WN);
    k_prep_wc<<<4096, 256, 0, stream>>>(w1, w3, w5, w7, Wc_t);
    k_prep_wh<<<128, 256, 0, stream>>>(Wmu, Wstd, Wh_t);

    k_gx<<<dim3(16, 12), 256, 0, stream>>>(xb, Wx_t, br, bz, bn, gxb);

    k_gru4<<<128, 1024, 0, stream>>>(WA, WN, gxb, hs);

    k_conv<<<dim3(16, 4, 20), 256, 0, stream>>>(hs, Wc_t, b1, b3, b5, b7, pa, ybuf);

    float* out_comm = (float*)d_out;
    float* out_lp   = (float*)d_out + (size_t)BDIM * LDIM * CDIM;
    k_head2<<<320, 256, 0, stream>>>(ybuf, Wh_t, bmu, bstd, eps, out_comm, lpsum);
    k_final<<<8, 256, 0, stream>>>(lpsum, out_lp);
}

// Round 12
// 1156.602 us; speedup vs baseline: 1.5510x; 1.2403x over previous
//
#include <hip/hip_runtime.h>
#include <hip/hip_bf16.h>

typedef __hip_bfloat16 bf16;
typedef short short8 __attribute__((ext_vector_type(8)));
typedef float floatx4 __attribute__((ext_vector_type(4)));

#define BDIM 2048   // E*S
#define HDIM 512
#define LDIM 20
#define CDIM 32
#define LSTR 40     // LDS row stride (bf16) for 32-wide tiles in gemm_tile_k
#define HPAD 520    // LDS row stride for 512-wide state rows (16B-aligned)

__device__ __forceinline__ float sigm(float x) { return 1.0f / (1.0f + expf(-x)); }

// ---------------------------------------------------------------------------
// Core 128x128 bf16 MFMA tile (k_gx / k_conv): C += A(128xK) @ Bt(128xK)^T
// Register-prefetched: chunk k0+32 is loaded while MFMAs run on chunk k0.
// ---------------------------------------------------------------------------
__device__ __forceinline__ void gemm_tile_k(
    const short* __restrict__ A, int lda,
    const short* __restrict__ Bt, int ldb,
    int K, short* lds, floatx4 (&acc)[4][4], int tid)
{
    short* As = lds;
    short* Bs = lds + 128 * LSTR;
    const int wave = tid >> 6, lane = tid & 63;
    const int wm = wave & 1, wn = wave >> 1;
    const int m16 = lane & 15, quad = lane >> 4;
    const int r0 = tid >> 2;
    const int koff = (tid & 3) * 8;

    short8 a0 = *(const short8*)(A + (size_t)r0 * lda + koff);
    short8 a1 = *(const short8*)(A + (size_t)(r0 + 64) * lda + koff);
    short8 b0 = *(const short8*)(Bt + (size_t)r0 * ldb + koff);
    short8 b1 = *(const short8*)(Bt + (size_t)(r0 + 64) * ldb + koff);
    for (int k0 = 0; k0 < K; k0 += 32) {
        __syncthreads();
        *(short8*)(As + r0 * LSTR + koff) = a0;
        *(short8*)(As + (r0 + 64) * LSTR + koff) = a1;
        *(short8*)(Bs + r0 * LSTR + koff) = b0;
        *(short8*)(Bs + (r0 + 64) * LSTR + koff) = b1;
        __syncthreads();
        if (k0 + 32 < K) {
            a0 = *(const short8*)(A + (size_t)r0 * lda + k0 + 32 + koff);
            a1 = *(const short8*)(A + (size_t)(r0 + 64) * lda + k0 + 32 + koff);
            b0 = *(const short8*)(Bt + (size_t)r0 * ldb + k0 + 32 + koff);
            b1 = *(const short8*)(Bt + (size_t)(r0 + 64) * ldb + k0 + 32 + koff);
        }
        short8 af[4], bfr[4];
#pragma unroll
        for (int i = 0; i < 4; ++i)
            af[i] = *(short8*)(As + (wm * 64 + i * 16 + m16) * LSTR + quad * 8);
#pragma unroll
        for (int j = 0; j < 4; ++j)
            bfr[j] = *(short8*)(Bs + (wn * 64 + j * 16 + m16) * LSTR + quad * 8);
#pragma unroll
        for (int i = 0; i < 4; ++i)
#pragma unroll
            for (int j = 0; j < 4; ++j)
                acc[i][j] = __builtin_amdgcn_mfma_f32_16x16x32_bf16(
                    af[i], bfr[j], acc[i][j], 0, 0, 0);
    }
}

// ---------------------------------------------------------------------------
// Prep kernels
// ---------------------------------------------------------------------------
__global__ __launch_bounds__(256) void k_prep_xb(const float* __restrict__ x,
                                                 bf16* __restrict__ xb)
{
    int i = blockIdx.x * 256 + threadIdx.x;
    xb[i] = (bf16)x[i];
}

__global__ __launch_bounds__(256) void k_transpose_512(const float* __restrict__ src,
                                                       bf16* __restrict__ dst)
{
    __shared__ float tile[32][33];
    int tx = threadIdx.x & 31, ty = threadIdx.x >> 5;
    int k0 = blockIdx.x * 32, n0 = blockIdx.y * 32;
#pragma unroll
    for (int i = 0; i < 32; i += 8)
        tile[ty + i][tx] = src[(size_t)(k0 + ty + i) * 512 + n0 + tx];
    __syncthreads();
#pragma unroll
    for (int i = 0; i < 32; i += 8)
        dst[(size_t)(n0 + ty + i) * 512 + k0 + tx] = (bf16)tile[tx][ty + i];
}

// h-part of [Wr|Wz] -> 16-wave 32-col B-fragment stream order:
// WA[(((kc*16 + w)*4 + f)*64 + lane)*8 + j]; f 0..1 = r cols, 2..3 = z cols.
__global__ __launch_bounds__(256) void k_swzA(const float* __restrict__ Wr,
                                              const float* __restrict__ Wz,
                                              bf16* __restrict__ WA)
{
    int idx = blockIdx.x * 256 + threadIdx.x;   // 0..524287
    int j = idx & 7, lane = (idx >> 3) & 63, f = (idx >> 9) & 3,
        w = (idx >> 11) & 15, kc = idx >> 15;
    int n = w * 32 + (f & 1) * 16 + (lane & 15);
    int k = kc * 32 + (lane >> 4) * 8 + j;
    float v = (f < 2) ? Wr[(size_t)(512 + k) * 512 + n]
                      : Wz[(size_t)(512 + k) * 512 + n];
    WA[idx] = (bf16)v;
}

// h-part of Wn: WN[(((kc*16 + w)*2 + f)*64 + lane)*8 + j]
__global__ __launch_bounds__(256) void k_swzN(const float* __restrict__ Wn,
                                              bf16* __restrict__ WN)
{
    int idx = blockIdx.x * 256 + threadIdx.x;   // 0..262143
    int j = idx & 7, lane = (idx >> 3) & 63, f = (idx >> 9) & 1,
        w = (idx >> 10) & 15, kc = idx >> 14;
    int n = w * 32 + f * 16 + (lane & 15);
    int k = kc * 32 + (lane >> 4) * 8 + j;
    WN[idx] = (bf16)Wn[(size_t)(512 + k) * 512 + n];
}

__global__ __launch_bounds__(256) void k_prep_wc(
    const float* __restrict__ w1, const float* __restrict__ w3,
    const float* __restrict__ w5, const float* __restrict__ w7,
    bf16* __restrict__ wt)
{
    int idx = blockIdx.x * 256 + threadIdx.x;
    int g, base;
    if (idx < 65536)       { g = 0; base = 0;      }
    else if (idx < 262144) { g = 1; base = 65536;  }
    else if (idx < 589824) { g = 2; base = 262144; }
    else                   { g = 3; base = 589824; }
    int rel = idx - base;
    int k = 2 * g + 1;
    int ci = rel & 511;
    int t2 = rel >> 9;
    int co = t2 & 127;
    int tap = t2 >> 7;
    const float* w = (g == 0) ? w1 : (g == 1) ? w3 : (g == 2) ? w5 : w7;
    wt[idx] = (bf16)w[((size_t)co * 512 + ci) * k + tap];
}

// [W_mu | W_std] (512x32 each) -> Wh_t[64][512] bf16 (transposed)
__global__ __launch_bounds__(256) void k_prep_wh(const float* __restrict__ Wmu,
                                                 const float* __restrict__ Wstd,
                                                 bf16* __restrict__ Wh_t)
{
    int idx = blockIdx.x * 256 + threadIdx.x;  // 0..32767
    int n = idx >> 9, k = idx & 511;
    float v = (n < 32) ? Wmu[(size_t)k * 32 + n] : Wstd[(size_t)k * 32 + (n - 32)];
    Wh_t[idx] = (bf16)v;
}

// ---------------------------------------------------------------------------
// gx = x @ [Wr_x | Wz_x | Wn_x] + [br|bz|bn]   (M=2048, N=1536, K=512) -> bf16
// ---------------------------------------------------------------------------
__global__ __launch_bounds__(256) void k_gx(
    const bf16* __restrict__ xb, const bf16* __restrict__ Wx_t,
    const float* __restrict__ br, const float* __restrict__ bz,
    const float* __restrict__ bn, bf16* __restrict__ gxb)
{
    __shared__ short lds[2 * 128 * LSTR];
    const int tid = threadIdx.x;
    const int row0 = blockIdx.x * 128, col0 = blockIdx.y * 128;
    floatx4 acc[4][4];
#pragma unroll
    for (int i = 0; i < 4; ++i)
#pragma unroll
        for (int j = 0; j < 4; ++j) acc[i][j] = (floatx4)0.0f;
    gemm_tile_k((const short*)xb + (size_t)row0 * 512, 512,
                (const short*)Wx_t + (size_t)col0 * 512, 512, 512, lds, acc, tid);
    const int wave = tid >> 6, lane = tid & 63;
    const int wm = wave & 1, wn = wave >> 1;
    const int m16 = lane & 15, quad = lane >> 4;
#pragma unroll
    for (int i = 0; i < 4; ++i)
#pragma unroll
        for (int j = 0; j < 4; ++j)
#pragma unroll
            for (int reg = 0; reg < 4; ++reg) {
                int b = row0 + wm * 64 + i * 16 + quad * 4 + reg;
                int n = col0 + wn * 64 + j * 16 + m16;
                float bias = (n < 512) ? br[n] : (n < 1024) ? bz[n - 512] : bn[n - 1024];
                gxb[(size_t)b * 1536 + n] = (bf16)(acc[i][j][reg] + bias);
            }
}

// ---------------------------------------------------------------------------
// Block-local GRU v4c: r8's best config (scattered hs store, depth-2 ring)
// + cross-phase prefetch hoisting: each phase's first two weight batches are
// issued BEFORE the preceding barrier/epilogue, so the weight stream never
// drains at a __syncthreads (hipBLASLt-style "vmcnt never 0").
// ---------------------------------------------------------------------------
__global__ __launch_bounds__(1024, 4) void k_gru4(
    const bf16* __restrict__ WA, const bf16* __restrict__ WN,
    const bf16* __restrict__ gxb, bf16* __restrict__ hs)
{
    __shared__ bf16 hb[16 * HPAD];
    __shared__ bf16 rh[16 * HPAD];
    const int tid = threadIdx.x;
    const int wave = tid >> 6, lane = tid & 63;
    const int m16 = lane & 15, quad = lane >> 4;
    const int rowbase = blockIdx.x * 16;
    const int colw = wave * 32;

    // step-invariant gx in registers
    float gxr[2][4], gxz[2][4], gxn[2][4];
#pragma unroll
    for (int f = 0; f < 2; ++f)
#pragma unroll
        for (int reg = 0; reg < 4; ++reg) {
            const bf16* gp = gxb + (size_t)(rowbase + quad * 4 + reg) * 1536;
            int col = colw + f * 16 + m16;
            gxr[f][reg] = __bfloat162float(gp[col]);
            gxz[f][reg] = __bfloat162float(gp[512 + col]);
            gxn[f][reg] = __bfloat162float(gp[1024 + col]);
        }

    for (int i = tid; i < 16 * HPAD; i += 1024) hb[i] = (bf16)0.0f;
    __syncthreads();

    const short8* WA8 = (const short8*)WA;  // kc*4096 + wave*256 + f*64 + lane
    const short8* WN8 = (const short8*)WN;  // kc*2048 + wave*128 + f*64 + lane
    const int ba = wave * 256 + lane;
    const int bn_ = wave * 128 + lane;

    float h32[2][4] = {};
    float zst[2][4];
    short8 cA0[4], cA1[4];   // phase-A prefetch ring head (loaded end of prev step)
    short8 dB0[2], dB1[2];   // phase-B prefetch ring head (loaded end of phase A)

    // prime phase-A batches for t=1 (t=0 skips the K-loop entirely)
#pragma unroll
    for (int f = 0; f < 4; ++f) cA0[f] = WA8[ba + f * 64];
#pragma unroll
    for (int f = 0; f < 4; ++f) cA1[f] = WA8[4096 + ba + f * 64];

    for (int t = 0; t < LDIM; ++t) {
        // ---------------- phase A: r,z ----------------
        floatx4 accR[2], accZ[2];
#pragma unroll
        for (int f = 0; f < 2; ++f) { accR[f] = (floatx4)0.0f; accZ[f] = (floatx4)0.0f; }
        if (t > 0) {
            short8 c2[4];
#pragma unroll
            for (int kc = 0; kc < 16; ++kc) {
                if (kc < 14) {
#pragma unroll
                    for (int f = 0; f < 4; ++f)
                        c2[f] = WA8[(size_t)(kc + 2) * 4096 + ba + f * 64];
                }
                short8 a = *(const short8*)((const short*)hb + m16 * HPAD + kc * 32 + quad * 8);
                accR[0] = __builtin_amdgcn_mfma_f32_16x16x32_bf16(a, cA0[0], accR[0], 0, 0, 0);
                accR[1] = __builtin_amdgcn_mfma_f32_16x16x32_bf16(a, cA0[1], accR[1], 0, 0, 0);
                accZ[0] = __builtin_amdgcn_mfma_f32_16x16x32_bf16(a, cA0[2], accZ[0], 0, 0, 0);
                accZ[1] = __builtin_amdgcn_mfma_f32_16x16x32_bf16(a, cA0[3], accZ[1], 0, 0, 0);
#pragma unroll
                for (int f = 0; f < 4; ++f) { cA0[f] = cA1[f]; cA1[f] = c2[f]; }
            }
        }
        // hoist: issue phase-B's first batches BEFORE epilogue + barrier
#pragma unroll
        for (int f = 0; f < 2; ++f) dB0[f] = WN8[bn_ + f * 64];
#pragma unroll
        for (int f = 0; f < 2; ++f) dB1[f] = WN8[2048 + bn_ + f * 64];
        // epilogue A: r,z; rh -> LDS; z stays in registers
#pragma unroll
        for (int f = 0; f < 2; ++f) {
            int col = colw + f * 16 + m16;
#pragma unroll
            for (int reg = 0; reg < 4; ++reg) {
                int row = quad * 4 + reg;
                float r = sigm(accR[f][reg] + gxr[f][reg]);
                zst[f][reg] = sigm(accZ[f][reg] + gxz[f][reg]);
                rh[row * HPAD + col] = (bf16)(r * h32[f][reg]);
            }
        }
        __syncthreads();
        // ---------------- phase B: n + state update ----------------
        floatx4 accN[2];
#pragma unroll
        for (int f = 0; f < 2; ++f) accN[f] = (floatx4)0.0f;
        if (t > 0) {
            short8 d2[2];
#pragma unroll
            for (int kc = 0; kc < 16; ++kc) {
                if (kc < 14) {
#pragma unroll
                    for (int f = 0; f < 2; ++f)
                        d2[f] = WN8[(size_t)(kc + 2) * 2048 + bn_ + f * 64];
                }
                short8 a = *(const short8*)((const short*)rh + m16 * HPAD + kc * 32 + quad * 8);
                accN[0] = __builtin_amdgcn_mfma_f32_16x16x32_bf16(a, dB0[0], accN[0], 0, 0, 0);
                accN[1] = __builtin_amdgcn_mfma_f32_16x16x32_bf16(a, dB0[1], accN[1], 0, 0, 0);
#pragma unroll
                for (int f = 0; f < 2; ++f) { dB0[f] = dB1[f]; dB1[f] = d2[f]; }
            }
        }
        // hoist: issue next step's phase-A batches BEFORE epilogue + barrier
#pragma unroll
        for (int f = 0; f < 4; ++f) cA0[f] = WA8[ba + f * 64];
#pragma unroll
        for (int f = 0; f < 4; ++f) cA1[f] = WA8[4096 + ba + f * 64];
#pragma unroll
        for (int f = 0; f < 2; ++f) {
            int col = colw + f * 16 + m16;
#pragma unroll
            for (int reg = 0; reg < 4; ++reg) {
                int row = quad * 4 + reg;
                float nv = tanhf(accN[f][reg] + gxn[f][reg]);
                float z = zst[f][reg];
                float hn = (1.0f - z) * nv + z * h32[f][reg];
                h32[f][reg] = hn;
                bf16 hv = (bf16)hn;
                hb[row * HPAD + col] = hv;
                hs[((size_t)t * BDIM + rowbase + row) * 512 + col] = hv;
            }
        }
        __syncthreads();
    }
}

// ---------------------------------------------------------------------------
// Multiscale conv as MFMA GEMM + bias + PReLU -> y bf16 (B, L, 512)
// ---------------------------------------------------------------------------
__global__ __launch_bounds__(256) void k_conv(
    const bf16* __restrict__ hs, const bf16* __restrict__ Wc_t,
    const float* __restrict__ b1, const float* __restrict__ b3,
    const float* __restrict__ b5, const float* __restrict__ b7,
    const float* __restrict__ pa, bf16* __restrict__ y)
{
    __shared__ short lds[2 * 128 * LSTR];
    const int tid = threadIdx.x;
    const int btile = blockIdx.x, g = blockIdx.y, l = blockIdx.z;
    const int row0 = btile * 128;
    const int ktap = 2 * g + 1, p = g;
    const int offs[4] = {0, 65536, 262144, 589824};
    const short* Wg = (const short*)Wc_t + offs[g];
    floatx4 acc[4][4];
#pragma unroll
    for (int i = 0; i < 4; ++i)
#pragma unroll
        for (int j = 0; j < 4; ++j) acc[i][j] = (floatx4)0.0f;
    for (int tap = 0; tap < ktap; ++tap) {
        int li = l + tap - p;
        if (li < 0 || li >= LDIM) continue;
        gemm_tile_k((const short*)hs + (size_t)li * BDIM * HDIM + (size_t)row0 * 512, 512,
                    Wg + (size_t)tap * 128 * 512, 512, 512, lds, acc, tid);
    }
    const float* bp = (g == 0) ? b1 : (g == 1) ? b3 : (g == 2) ? b5 : b7;
    const float a = *pa;
    const int wave = tid >> 6, lane = tid & 63;
    const int wm = wave & 1, wn = wave >> 1;
    const int m16 = lane & 15, quad = lane >> 4;
#pragma unroll
    for (int i = 0; i < 4; ++i)
#pragma unroll
        for (int j = 0; j < 4; ++j)
#pragma unroll
            for (int reg = 0; reg < 4; ++reg) {
                int b = row0 + wm * 64 + i * 16 + quad * 4 + reg;
                int col = wn * 64 + j * 16 + m16;
                float v = acc[i][j][reg] + bp[col];
                v = (v >= 0.0f) ? v : a * v;
                y[((size_t)b * LDIM + l) * 512 + g * 128 + col] = (bf16)v;
            }
}

// ---------------------------------------------------------------------------
// Head as MFMA GEMM: (40960 x 64) = y(40960x512) @ [Wmu|Wstd]^T, fused sample+lp
// ---------------------------------------------------------------------------
__global__ __launch_bounds__(256) void k_head2(
    const bf16* __restrict__ y, const bf16* __restrict__ Wh_t,
    const float* __restrict__ bmu, const float* __restrict__ bstd,
    const float* __restrict__ eps, float* __restrict__ out_comm,
    float* __restrict__ lpsum)
{
    __shared__ short As[128 * LSTR];
    __shared__ short Bs[64 * LSTR];
    const int tid = threadIdx.x;
    const int wave = tid >> 6, lane = tid & 63;
    const int m16 = lane & 15, quad = lane >> 4;
    const int r0 = tid >> 2, koff = (tid & 3) * 8;
    const int row0 = blockIdx.x * 128;
    floatx4 acc[2][4];
#pragma unroll
    for (int i = 0; i < 2; ++i)
#pragma unroll
        for (int j = 0; j < 4; ++j) acc[i][j] = (floatx4)0.0f;
    const short* Ap = (const short*)y + (size_t)row0 * 512;
    const short* Bp = (const short*)Wh_t;
    short8 ga0 = *(const short8*)(Ap + (size_t)r0 * 512 + koff);
    short8 ga1 = *(const short8*)(Ap + (size_t)(r0 + 64) * 512 + koff);
    short8 gb0 = *(const short8*)(Bp + (size_t)r0 * 512 + koff);
    for (int k0 = 0; k0 < 512; k0 += 32) {
        __syncthreads();
        *(short8*)(As + r0 * LSTR + koff) = ga0;
        *(short8*)(As + (r0 + 64) * LSTR + koff) = ga1;
        *(short8*)(Bs + r0 * LSTR + koff) = gb0;
        __syncthreads();
        if (k0 + 32 < 512) {
            ga0 = *(const short8*)(Ap + (size_t)r0 * 512 + k0 + 32 + koff);
            ga1 = *(const short8*)(Ap + (size_t)(r0 + 64) * 512 + k0 + 32 + koff);
            gb0 = *(const short8*)(Bp + (size_t)r0 * 512 + k0 + 32 + koff);
        }
        short8 af[2], bfr[4];
#pragma unroll
        for (int i = 0; i < 2; ++i)
            af[i] = *(short8*)(As + (wave * 32 + i * 16 + m16) * LSTR + quad * 8);
#pragma unroll
        for (int j = 0; j < 4; ++j)
            bfr[j] = *(short8*)(Bs + (j * 16 + m16) * LSTR + quad * 8);
#pragma unroll
        for (int i = 0; i < 2; ++i)
#pragma unroll
            for (int j = 0; j < 4; ++j)
                acc[i][j] = __builtin_amdgcn_mfma_f32_16x16x32_bf16(
                    af[i], bfr[j], acc[i][j], 0, 0, 0);
    }
#pragma unroll
    for (int i = 0; i < 2; ++i)
#pragma unroll
        for (int reg = 0; reg < 4; ++reg) {
            int row = row0 + wave * 32 + i * 16 + quad * 4 + reg;
            float lp = 0.0f;
#pragma unroll
            for (int jj = 0; jj < 2; ++jj) {
                int c = jj * 16 + m16;
                float mu = acc[i][jj][reg] + bmu[c];
                float sraw = acc[i][jj + 2][reg] + bstd[c];
                float sp = (sraw > 20.0f) ? sraw : log1pf(expf(sraw));
                float sd = fminf(fmaxf(sp, 2.0611536e-09f), 7.389056f);
                float e = eps[(size_t)row * 32 + c];
                float comm = fmaf(e, sd, mu);
                float tt = tanhf(comm);
                out_comm[(size_t)row * 32 + c] = tt;
                lp += -0.5f * e * e - logf(sd) - 0.91893853320467274f
                      - logf(1.0f - tt * tt + 1e-6f);
            }
            lp += __shfl_xor(lp, 1, 16);
            lp += __shfl_xor(lp, 2, 16);
            lp += __shfl_xor(lp, 4, 16);
            lp += __shfl_xor(lp, 8, 16);
            if (m16 == 0) lpsum[row] = lp;
        }
}

__global__ __launch_bounds__(256) void k_final(const float* __restrict__ lpsum,
                                               float* __restrict__ out2)
{
    int b = blockIdx.x * 256 + threadIdx.x;
    if (b < BDIM) {
        float s = 0.0f;
#pragma unroll
        for (int i = 0; i < LDIM; ++i) s += lpsum[b * LDIM + i];
        out2[b] = s * (1.0f / (LDIM * CDIM));
    }
}

// ---------------------------------------------------------------------------
extern "C" void kernel_launch(void* const* d_in, const int* in_sizes, int n_in,
                              void* d_out, int out_size, void* d_ws, size_t ws_size,
                              hipStream_t stream)
{
    const float* x    = (const float*)d_in[0];
    const float* Wr   = (const float*)d_in[1];
    const float* br   = (const float*)d_in[2];
    const float* Wz   = (const float*)d_in[3];
    const float* bz   = (const float*)d_in[4];
    const float* Wn   = (const float*)d_in[5];
    const float* bn   = (const float*)d_in[6];
    const float* w1   = (const float*)d_in[7];
    const float* b1   = (const float*)d_in[8];
    const float* w3   = (const float*)d_in[9];
    const float* b3   = (const float*)d_in[10];
    const float* w5   = (const float*)d_in[11];
    const float* b5   = (const float*)d_in[12];
    const float* w7   = (const float*)d_in[13];
    const float* b7   = (const float*)d_in[14];
    const float* pa   = (const float*)d_in[15];
    const float* Wmu  = (const float*)d_in[16];
    const float* bmu  = (const float*)d_in[17];
    const float* Wstd = (const float*)d_in[18];
    const float* bstd = (const float*)d_in[19];
    const float* eps  = (const float*)d_in[20];

    char* cur = (char*)d_ws;
    auto alloc = [&](size_t bytes) -> void* {
        void* r = (void*)cur;
        cur += (bytes + 255) & ~(size_t)255;
        return r;
    };
    const size_t BH = (size_t)BDIM * HDIM;
    bf16*  gxb   = (bf16*)alloc((size_t)BDIM * 1536 * 2);
    bf16*  xb    = (bf16*)alloc(BH * 2);
    bf16*  hs    = (bf16*)alloc(BH * LDIM * 2);
    bf16*  ybuf  = (bf16*)alloc(BH * LDIM * 2);
    bf16*  Wx_t  = (bf16*)alloc((size_t)1536 * 512 * 2);
    bf16*  WA    = (bf16*)alloc((size_t)524288 * 2);
    bf16*  WN    = (bf16*)alloc((size_t)262144 * 2);
    bf16*  Wc_t  = (bf16*)alloc((size_t)1048576 * 2);
    bf16*  Wh_t  = (bf16*)alloc((size_t)64 * 512 * 2);
    float* lpsum = (float*)alloc((size_t)BDIM * LDIM * 4);

    k_prep_xb<<<4096, 256, 0, stream>>>(x, xb);
    dim3 tg(16, 16);
    k_transpose_512<<<tg, 256, 0, stream>>>(Wr, Wx_t);         // x-half of Wr
    k_transpose_512<<<tg, 256, 0, stream>>>(Wz, Wx_t + 262144);
    k_transpose_512<<<tg, 256, 0, stream>>>(Wn, Wx_t + 524288);
    k_swzA<<<2048, 256, 0, stream>>>(Wr, Wz, WA);
    k_swzN<<<1024, 256, 0, stream>>>(Wn, WN);
    k_prep_wc<<<4096, 256, 0, stream>>>(w1, w3, w5, w7, Wc_t);
    k_prep_wh<<<128, 256, 0, stream>>>(Wmu, Wstd, Wh_t);

    k_gx<<<dim3(16, 12), 256, 0, stream>>>(xb, Wx_t, br, bz, bn, gxb);

    k_gru4<<<128, 1024, 0, stream>>>(WA, WN, gxb, hs);

    k_conv<<<dim3(16, 4, 20), 256, 0, stream>>>(hs, Wc_t, b1, b3, b5, b7, pa, ybuf);

    float* out_comm = (float*)d_out;
    float* out_lp   = (float*)d_out + (size_t)BDIM * LDIM * CDIM;
    k_head2<<<320, 256, 0, stream>>>(ybuf, Wh_t, bmu, bstd, eps, out_comm, lpsum);
    k_final<<<8, 256, 0, stream>>>(lpsum, out_lp);
}

// Round 13
// 1055.804 us; speedup vs baseline: 1.6991x; 1.0955x over previous
//
#include <hip/hip_runtime.h>
#include <hip/hip_bf16.h>

typedef __hip_bfloat16 bf16;
typedef short short8 __attribute__((ext_vector_type(8)));
typedef float floatx4 __attribute__((ext_vector_type(4)));

#define BDIM 2048   // E*S
#define HDIM 512
#define LDIM 20
#define CDIM 32
#define LSTR 40     // LDS row stride (bf16) for 32-wide tiles in gemm_tile_k
#define HPAD 520    // LDS row stride for 512-wide state rows (16B-aligned)

__device__ __forceinline__ float sigm(float x) { return 1.0f / (1.0f + expf(-x)); }

// async global->LDS, 16 B per lane; lds base must be wave-uniform, HW strides by lane*16
__device__ __forceinline__ void ll16(const short* g, short* l)
{
    __builtin_amdgcn_global_load_lds(
        (const __attribute__((address_space(1))) void*)g,
        (__attribute__((address_space(3))) void*)l, 16, 0, 0);
}
#define WAITVM(N) asm volatile("s_waitcnt vmcnt(" #N ")" ::: "memory")

// ---------------------------------------------------------------------------
// Core 128x128 bf16 MFMA tile (k_gx / k_conv): C += A(128xK) @ Bt(128xK)^T
// ---------------------------------------------------------------------------
__device__ __forceinline__ void gemm_tile_k(
    const short* __restrict__ A, int lda,
    const short* __restrict__ Bt, int ldb,
    int K, short* lds, floatx4 (&acc)[4][4], int tid)
{
    short* As = lds;
    short* Bs = lds + 128 * LSTR;
    const int wave = tid >> 6, lane = tid & 63;
    const int wm = wave & 1, wn = wave >> 1;
    const int m16 = lane & 15, quad = lane >> 4;
    const int r0 = tid >> 2;
    const int koff = (tid & 3) * 8;

    short8 a0 = *(const short8*)(A + (size_t)r0 * lda + koff);
    short8 a1 = *(const short8*)(A + (size_t)(r0 + 64) * lda + koff);
    short8 b0 = *(const short8*)(Bt + (size_t)r0 * ldb + koff);
    short8 b1 = *(const short8*)(Bt + (size_t)(r0 + 64) * ldb + koff);
    for (int k0 = 0; k0 < K; k0 += 32) {
        __syncthreads();
        *(short8*)(As + r0 * LSTR + koff) = a0;
        *(short8*)(As + (r0 + 64) * LSTR + koff) = a1;
        *(short8*)(Bs + r0 * LSTR + koff) = b0;
        *(short8*)(Bs + (r0 + 64) * LSTR + koff) = b1;
        __syncthreads();
        if (k0 + 32 < K) {
            a0 = *(const short8*)(A + (size_t)r0 * lda + k0 + 32 + koff);
            a1 = *(const short8*)(A + (size_t)(r0 + 64) * lda + k0 + 32 + koff);
            b0 = *(const short8*)(Bt + (size_t)r0 * ldb + k0 + 32 + koff);
            b1 = *(const short8*)(Bt + (size_t)(r0 + 64) * ldb + k0 + 32 + koff);
        }
        short8 af[4], bfr[4];
#pragma unroll
        for (int i = 0; i < 4; ++i)
            af[i] = *(short8*)(As + (wm * 64 + i * 16 + m16) * LSTR + quad * 8);
#pragma unroll
        for (int j = 0; j < 4; ++j)
            bfr[j] = *(short8*)(Bs + (wn * 64 + j * 16 + m16) * LSTR + quad * 8);
#pragma unroll
        for (int i = 0; i < 4; ++i)
#pragma unroll
            for (int j = 0; j < 4; ++j)
                acc[i][j] = __builtin_amdgcn_mfma_f32_16x16x32_bf16(
                    af[i], bfr[j], acc[i][j], 0, 0, 0);
    }
}

// ---------------------------------------------------------------------------
// Prep kernels
// ---------------------------------------------------------------------------
__global__ __launch_bounds__(256) void k_prep_xb(const float* __restrict__ x,
                                                 bf16* __restrict__ xb)
{
    int i = blockIdx.x * 256 + threadIdx.x;
    xb[i] = (bf16)x[i];
}

__global__ __launch_bounds__(256) void k_transpose_512(const float* __restrict__ src,
                                                       bf16* __restrict__ dst)
{
    __shared__ float tile[32][33];
    int tx = threadIdx.x & 31, ty = threadIdx.x >> 5;
    int k0 = blockIdx.x * 32, n0 = blockIdx.y * 32;
#pragma unroll
    for (int i = 0; i < 32; i += 8)
        tile[ty + i][tx] = src[(size_t)(k0 + ty + i) * 512 + n0 + tx];
    __syncthreads();
#pragma unroll
    for (int i = 0; i < 32; i += 8)
        dst[(size_t)(n0 + ty + i) * 512 + k0 + tx] = (bf16)tile[tx][ty + i];
}

// h-part of [Wr|Wz] -> 16-wave 32-col B-fragment stream order:
// WA[(((kc*16 + w)*4 + f)*64 + lane)*8 + j]; f 0..1 = r cols, 2..3 = z cols.
__global__ __launch_bounds__(256) void k_swzA(const float* __restrict__ Wr,
                                              const float* __restrict__ Wz,
                                              bf16* __restrict__ WA)
{
    int idx = blockIdx.x * 256 + threadIdx.x;   // 0..524287
    int j = idx & 7, lane = (idx >> 3) & 63, f = (idx >> 9) & 3,
        w = (idx >> 11) & 15, kc = idx >> 15;
    int n = w * 32 + (f & 1) * 16 + (lane & 15);
    int k = kc * 32 + (lane >> 4) * 8 + j;
    float v = (f < 2) ? Wr[(size_t)(512 + k) * 512 + n]
                      : Wz[(size_t)(512 + k) * 512 + n];
    WA[idx] = (bf16)v;
}

// h-part of Wn: WN[(((kc*16 + w)*2 + f)*64 + lane)*8 + j]
__global__ __launch_bounds__(256) void k_swzN(const float* __restrict__ Wn,
                                              bf16* __restrict__ WN)
{
    int idx = blockIdx.x * 256 + threadIdx.x;   // 0..262143
    int j = idx & 7, lane = (idx >> 3) & 63, f = (idx >> 9) & 1,
        w = (idx >> 10) & 15, kc = idx >> 14;
    int n = w * 32 + f * 16 + (lane & 15);
    int k = kc * 32 + (lane >> 4) * 8 + j;
    WN[idx] = (bf16)Wn[(size_t)(512 + k) * 512 + n];
}

__global__ __launch_bounds__(256) void k_prep_wc(
    const float* __restrict__ w1, const float* __restrict__ w3,
    const float* __restrict__ w5, const float* __restrict__ w7,
    bf16* __restrict__ wt)
{
    int idx = blockIdx.x * 256 + threadIdx.x;
    int g, base;
    if (idx < 65536)       { g = 0; base = 0;      }
    else if (idx < 262144) { g = 1; base = 65536;  }
    else if (idx < 589824) { g = 2; base = 262144; }
    else                   { g = 3; base = 589824; }
    int rel = idx - base;
    int k = 2 * g + 1;
    int ci = rel & 511;
    int t2 = rel >> 9;
    int co = t2 & 127;
    int tap = t2 >> 7;
    const float* w = (g == 0) ? w1 : (g == 1) ? w3 : (g == 2) ? w5 : w7;
    wt[idx] = (bf16)w[((size_t)co * 512 + ci) * k + tap];
}

// [W_mu | W_std] (512x32 each) -> Wh_t[64][512] bf16 (transposed)
__global__ __launch_bounds__(256) void k_prep_wh(const float* __restrict__ Wmu,
                                                 const float* __restrict__ Wstd,
                                                 bf16* __restrict__ Wh_t)
{
    int idx = blockIdx.x * 256 + threadIdx.x;  // 0..32767
    int n = idx >> 9, k = idx & 511;
    float v = (n < 32) ? Wmu[(size_t)k * 32 + n] : Wstd[(size_t)k * 32 + (n - 32)];
    Wh_t[idx] = (bf16)v;
}

// ---------------------------------------------------------------------------
// gx = x @ [Wr_x | Wz_x | Wn_x] + [br|bz|bn]   (M=2048, N=1536, K=512) -> bf16
// ---------------------------------------------------------------------------
__global__ __launch_bounds__(256) void k_gx(
    const bf16* __restrict__ xb, const bf16* __restrict__ Wx_t,
    const float* __restrict__ br, const float* __restrict__ bz,
    const float* __restrict__ bn, bf16* __restrict__ gxb)
{
    __shared__ short lds[2 * 128 * LSTR];
    const int tid = threadIdx.x;
    const int row0 = blockIdx.x * 128, col0 = blockIdx.y * 128;
    floatx4 acc[4][4];
#pragma unroll
    for (int i = 0; i < 4; ++i)
#pragma unroll
        for (int j = 0; j < 4; ++j) acc[i][j] = (floatx4)0.0f;
    gemm_tile_k((const short*)xb + (size_t)row0 * 512, 512,
                (const short*)Wx_t + (size_t)col0 * 512, 512, 512, lds, acc, tid);
    const int wave = tid >> 6, lane = tid & 63;
    const int wm = wave & 1, wn = wave >> 1;
    const int m16 = lane & 15, quad = lane >> 4;
#pragma unroll
    for (int i = 0; i < 4; ++i)
#pragma unroll
        for (int j = 0; j < 4; ++j)
#pragma unroll
            for (int reg = 0; reg < 4; ++reg) {
                int b = row0 + wm * 64 + i * 16 + quad * 4 + reg;
                int n = col0 + wn * 64 + j * 16 + m16;
                float bias = (n < 512) ? br[n] : (n < 1024) ? bz[n - 512] : bn[n - 1024];
                gxb[(size_t)b * 1536 + n] = (bf16)(acc[i][j][reg] + bias);
            }
}

// ---------------------------------------------------------------------------
// GRU v6: r8 skeleton + async weight stream via global_load_lds.
// 128 blocks x 16 rows x 1024 thr (16 waves, wave owns 32 cols of r/z/n).
// Weights DMA'd into a 2x64KB LDS ring (per-wave private slots -> NO barrier
// in the K-loop); explicit s_waitcnt vmcnt(4/2/0) gives a depth-2 chunk
// pipeline whose outstanding data lives in the HW queue, not VGPRs.
// rh overlaid into unused ring space (phase B uses only [0:16384) per slot).
// ---------------------------------------------------------------------------
__global__ __launch_bounds__(1024, 4) void k_gru6(
    const bf16* __restrict__ WA, const bf16* __restrict__ WN,
    const bf16* __restrict__ gxb, bf16* __restrict__ hs)
{
    __shared__ short wbuf[2][32768];   // 128 KB weight ring
    __shared__ short hb[16 * HPAD];    // 16.6 KB h state (bf16 bits)
    short* rhp = &wbuf[0][16384];      // rh overlay (phase-B-dead region)
    const int tid = threadIdx.x;
    const int wave = tid >> 6, lane = tid & 63;
    const int m16 = lane & 15, quad = lane >> 4;
    const int rowbase = blockIdx.x * 16;
    const int colw = wave * 32;
    const short* WAs = (const short*)WA;
    const short* WNs = (const short*)WN;

    // step-invariant gx in registers
    float gxr[2][4], gxz[2][4], gxn[2][4];
#pragma unroll
    for (int f = 0; f < 2; ++f)
#pragma unroll
        for (int reg = 0; reg < 4; ++reg) {
            const bf16* gp = gxb + (size_t)(rowbase + quad * 4 + reg) * 1536;
            int col = colw + f * 16 + m16;
            gxr[f][reg] = __bfloat162float(gp[col]);
            gxz[f][reg] = __bfloat162float(gp[512 + col]);
            gxn[f][reg] = __bfloat162float(gp[1024 + col]);
        }

    for (int i = tid; i < 16 * HPAD; i += 1024) hb[i] = 0;
    __syncthreads();

    float h32[2][4] = {};
    float zst[2][4];

    for (int t = 0; t < LDIM; ++t) {
        // ---------------- phase A: r,z ----------------
        floatx4 accR[2], accZ[2];
#pragma unroll
        for (int f = 0; f < 2; ++f) { accR[f] = (floatx4)0.0f; accZ[f] = (floatx4)0.0f; }
        if (t > 0) {
            // chunks 0,1 were primed at end of previous step (drained by S4)
#pragma unroll
            for (int kc = 0; kc < 16; ++kc) {
                if (kc < 15) { WAITVM(4); } else { WAITVM(0); }
                short8 bfr[4];
#pragma unroll
                for (int f = 0; f < 4; ++f)
                    bfr[f] = *(short8*)&wbuf[kc & 1][((wave * 4 + f) << 9) + lane * 8];
                short8 a = *(const short8*)(hb + m16 * HPAD + kc * 32 + quad * 8);
                accR[0] = __builtin_amdgcn_mfma_f32_16x16x32_bf16(a, bfr[0], accR[0], 0, 0, 0);
                accR[1] = __builtin_amdgcn_mfma_f32_16x16x32_bf16(a, bfr[1], accR[1], 0, 0, 0);
                accZ[0] = __builtin_amdgcn_mfma_f32_16x16x32_bf16(a, bfr[2], accZ[0], 0, 0, 0);
                accZ[1] = __builtin_amdgcn_mfma_f32_16x16x32_bf16(a, bfr[3], accZ[1], 0, 0, 0);
                if (kc < 14) {
#pragma unroll
                    for (int f = 0; f < 4; ++f)
                        ll16(WAs + (size_t)((((kc + 2) * 16 + wave) * 4 + f) << 9) + lane * 8,
                             &wbuf[kc & 1][(wave * 4 + f) << 9]);
                }
            }
        }
        __syncthreads();  // S1: all A-chunk reads done
        if (t > 0) {      // prime phase-B chunks 0,1 (consumed this step)
#pragma unroll
            for (int f = 0; f < 2; ++f) {
                ll16(WNs + (size_t)(((0 * 16 + wave) * 2 + f) << 9) + lane * 8,
                     &wbuf[0][(wave * 2 + f) << 9]);
                ll16(WNs + (size_t)(((1 * 16 + wave) * 2 + f) << 9) + lane * 8,
                     &wbuf[1][(wave * 2 + f) << 9]);
            }
        }
        // epilogue A: r,z; rh -> overlay; z stays in registers
#pragma unroll
        for (int f = 0; f < 2; ++f) {
            int col = colw + f * 16 + m16;
#pragma unroll
            for (int reg = 0; reg < 4; ++reg) {
                int row = quad * 4 + reg;
                float r = sigm(accR[f][reg] + gxr[f][reg]);
                zst[f][reg] = sigm(accZ[f][reg] + gxz[f][reg]);
                rhp[row * HPAD + col] = (short)__bfloat16_as_ushort(
                    (bf16)(r * h32[f][reg]));
            }
        }
        __syncthreads();  // S2: rh visible, B chunks drained
        // ---------------- phase B: n ----------------
        floatx4 accN[2];
#pragma unroll
        for (int f = 0; f < 2; ++f) accN[f] = (floatx4)0.0f;
        if (t > 0) {
#pragma unroll
            for (int kc = 0; kc < 16; ++kc) {
                if (kc < 15) { WAITVM(2); } else { WAITVM(0); }
                short8 bfr[2];
#pragma unroll
                for (int f = 0; f < 2; ++f)
                    bfr[f] = *(short8*)&wbuf[kc & 1][((wave * 2 + f) << 9) + lane * 8];
                short8 a = *(const short8*)(rhp + m16 * HPAD + kc * 32 + quad * 8);
                accN[0] = __builtin_amdgcn_mfma_f32_16x16x32_bf16(a, bfr[0], accN[0], 0, 0, 0);
                accN[1] = __builtin_amdgcn_mfma_f32_16x16x32_bf16(a, bfr[1], accN[1], 0, 0, 0);
                if (kc < 14) {
#pragma unroll
                    for (int f = 0; f < 2; ++f)
                        ll16(WNs + (size_t)((((kc + 2) * 16 + wave) * 2 + f) << 9) + lane * 8,
                             &wbuf[kc & 1][(wave * 2 + f) << 9]);
                }
            }
        }
        __syncthreads();  // S3: all B reads of wbuf/rhp done
        if (t < LDIM - 1) {  // prime next step's phase-A chunks 0,1
#pragma unroll
            for (int f = 0; f < 4; ++f) {
                ll16(WAs + (size_t)(((0 * 16 + wave) * 4 + f) << 9) + lane * 8,
                     &wbuf[0][(wave * 4 + f) << 9]);
                ll16(WAs + (size_t)(((1 * 16 + wave) * 4 + f) << 9) + lane * 8,
                     &wbuf[1][(wave * 4 + f) << 9]);
            }
        }
        // epilogue B: n, state update, hs write (r8-style scattered stores)
#pragma unroll
        for (int f = 0; f < 2; ++f) {
            int col = colw + f * 16 + m16;
#pragma unroll
            for (int reg = 0; reg < 4; ++reg) {
                int row = quad * 4 + reg;
                float nv = tanhf(accN[f][reg] + gxn[f][reg]);
                float z = zst[f][reg];
                float hn = (1.0f - z) * nv + z * h32[f][reg];
                h32[f][reg] = hn;
                bf16 hv = (bf16)hn;
                hb[row * HPAD + col] = (short)__bfloat16_as_ushort(hv);
                hs[((size_t)t * BDIM + rowbase + row) * 512 + col] = hv;
            }
        }
        __syncthreads();  // S4: hb visible for next phase A (also drains primes)
    }
}

// ---------------------------------------------------------------------------
// Multiscale conv as MFMA GEMM + bias + PReLU -> y bf16 (B, L, 512)
// ---------------------------------------------------------------------------
__global__ __launch_bounds__(256) void k_conv(
    const bf16* __restrict__ hs, const bf16* __restrict__ Wc_t,
    const float* __restrict__ b1, const float* __restrict__ b3,
    const float* __restrict__ b5, const float* __restrict__ b7,
    const float* __restrict__ pa, bf16* __restrict__ y)
{
    __shared__ short lds[2 * 128 * LSTR];
    const int tid = threadIdx.x;
    const int btile = blockIdx.x, g = blockIdx.y, l = blockIdx.z;
    const int row0 = btile * 128;
    const int ktap = 2 * g + 1, p = g;
    const int offs[4] = {0, 65536, 262144, 589824};
    const short* Wg = (const short*)Wc_t + offs[g];
    floatx4 acc[4][4];
#pragma unroll
    for (int i = 0; i < 4; ++i)
#pragma unroll
        for (int j = 0; j < 4; ++j) acc[i][j] = (floatx4)0.0f;
    for (int tap = 0; tap < ktap; ++tap) {
        int li = l + tap - p;
        if (li < 0 || li >= LDIM) continue;
        gemm_tile_k((const short*)hs + (size_t)li * BDIM * HDIM + (size_t)row0 * 512, 512,
                    Wg + (size_t)tap * 128 * 512, 512, 512, lds, acc, tid);
    }
    const float* bp = (g == 0) ? b1 : (g == 1) ? b3 : (g == 2) ? b5 : b7;
    const float a = *pa;
    const int wave = tid >> 6, lane = tid & 63;
    const int wm = wave & 1, wn = wave >> 1;
    const int m16 = lane & 15, quad = lane >> 4;
#pragma unroll
    for (int i = 0; i < 4; ++i)
#pragma unroll
        for (int j = 0; j < 4; ++j)
#pragma unroll
            for (int reg = 0; reg < 4; ++reg) {
                int b = row0 + wm * 64 + i * 16 + quad * 4 + reg;
                int col = wn * 64 + j * 16 + m16;
                float v = acc[i][j][reg] + bp[col];
                v = (v >= 0.0f) ? v : a * v;
                y[((size_t)b * LDIM + l) * 512 + g * 128 + col] = (bf16)v;
            }
}

// ---------------------------------------------------------------------------
// Head as MFMA GEMM: (40960 x 64) = y(40960x512) @ [Wmu|Wstd]^T, fused sample+lp
// ---------------------------------------------------------------------------
__global__ __launch_bounds__(256) void k_head2(
    const bf16* __restrict__ y, const bf16* __restrict__ Wh_t,
    const float* __restrict__ bmu, const float* __restrict__ bstd,
    const float* __restrict__ eps, float* __restrict__ out_comm,
    float* __restrict__ lpsum)
{
    __shared__ short As[128 * LSTR];
    __shared__ short Bs[64 * LSTR];
    const int tid = threadIdx.x;
    const int wave = tid >> 6, lane = tid & 63;
    const int m16 = lane & 15, quad = lane >> 4;
    const int r0 = tid >> 2, koff = (tid & 3) * 8;
    const int row0 = blockIdx.x * 128;
    floatx4 acc[2][4];
#pragma unroll
    for (int i = 0; i < 2; ++i)
#pragma unroll
        for (int j = 0; j < 4; ++j) acc[i][j] = (floatx4)0.0f;
    const short* Ap = (const short*)y + (size_t)row0 * 512;
    const short* Bp = (const short*)Wh_t;
    short8 ga0 = *(const short8*)(Ap + (size_t)r0 * 512 + koff);
    short8 ga1 = *(const short8*)(Ap + (size_t)(r0 + 64) * 512 + koff);
    short8 gb0 = *(const short8*)(Bp + (size_t)r0 * 512 + koff);
    for (int k0 = 0; k0 < 512; k0 += 32) {
        __syncthreads();
        *(short8*)(As + r0 * LSTR + koff) = ga0;
        *(short8*)(As + (r0 + 64) * LSTR + koff) = ga1;
        *(short8*)(Bs + r0 * LSTR + koff) = gb0;
        __syncthreads();
        if (k0 + 32 < 512) {
            ga0 = *(const short8*)(Ap + (size_t)r0 * 512 + k0 + 32 + koff);
            ga1 = *(const short8*)(Ap + (size_t)(r0 + 64) * 512 + k0 + 32 + koff);
            gb0 = *(const short8*)(Bp + (size_t)r0 * 512 + k0 + 32 + koff);
        }
        short8 af[2], bfr[4];
#pragma unroll
        for (int i = 0; i < 2; ++i)
            af[i] = *(short8*)(As + (wave * 32 + i * 16 + m16) * LSTR + quad * 8);
#pragma unroll
        for (int j = 0; j < 4; ++j)
            bfr[j] = *(short8*)(Bs + (j * 16 + m16) * LSTR + quad * 8);
#pragma unroll
        for (int i = 0; i < 2; ++i)
#pragma unroll
            for (int j = 0; j < 4; ++j)
                acc[i][j] = __builtin_amdgcn_mfma_f32_16x16x32_bf16(
                    af[i], bfr[j], acc[i][j], 0, 0, 0);
    }
#pragma unroll
    for (int i = 0; i < 2; ++i)
#pragma unroll
        for (int reg = 0; reg < 4; ++reg) {
            int row = row0 + wave * 32 + i * 16 + quad * 4 + reg;
            float lp = 0.0f;
#pragma unroll
            for (int jj = 0; jj < 2; ++jj) {
                int c = jj * 16 + m16;
                float mu = acc[i][jj][reg] + bmu[c];
                float sraw = acc[i][jj + 2][reg] + bstd[c];
                float sp = (sraw > 20.0f) ? sraw : log1pf(expf(sraw));
                float sd = fminf(fmaxf(sp, 2.0611536e-09f), 7.389056f);
                float e = eps[(size_t)row * 32 + c];
                float comm = fmaf(e, sd, mu);
                float tt = tanhf(comm);
                out_comm[(size_t)row * 32 + c] = tt;
                lp += -0.5f * e * e - logf(sd) - 0.91893853320467274f
                      - logf(1.0f - tt * tt + 1e-6f);
            }
            lp += __shfl_xor(lp, 1, 16);
            lp += __shfl_xor(lp, 2, 16);
            lp += __shfl_xor(lp, 4, 16);
            lp += __shfl_xor(lp, 8, 16);
            if (m16 == 0) lpsum[row] = lp;
        }
}

__global__ __launch_bounds__(256) void k_final(const float* __restrict__ lpsum,
                                               float* __restrict__ out2)
{
    int b = blockIdx.x * 256 + threadIdx.x;
    if (b < BDIM) {
        float s = 0.0f;
#pragma unroll
        for (int i = 0; i < LDIM; ++i) s += lpsum[b * LDIM + i];
        out2[b] = s * (1.0f / (LDIM * CDIM));
    }
}

// ---------------------------------------------------------------------------
extern "C" void kernel_launch(void* const* d_in, const int* in_sizes, int n_in,
                              void* d_out, int out_size, void* d_ws, size_t ws_size,
                              hipStream_t stream)
{
    const float* x    = (const float*)d_in[0];
    const float* Wr   = (const float*)d_in[1];
    const float* br   = (const float*)d_in[2];
    const float* Wz   = (const float*)d_in[3];
    const float* bz   = (const float*)d_in[4];
    const float* Wn   = (const float*)d_in[5];
    const float* bn   = (const float*)d_in[6];
    const float* w1   = (const float*)d_in[7];
    const float* b1   = (const float*)d_in[8];
    const float* w3   = (const float*)d_in[9];
    const float* b3   = (const float*)d_in[10];
    const float* w5   = (const float*)d_in[11];
    const float* b5   = (const float*)d_in[12];
    const float* w7   = (const float*)d_in[13];
    const float* b7   = (const float*)d_in[14];
    const float* pa   = (const float*)d_in[15];
    const float* Wmu  = (const float*)d_in[16];
    const float* bmu  = (const float*)d_in[17];
    const float* Wstd = (const float*)d_in[18];
    const float* bstd = (const float*)d_in[19];
    const float* eps  = (const float*)d_in[20];

    char* cur = (char*)d_ws;
    auto alloc = [&](size_t bytes) -> void* {
        void* r = (void*)cur;
        cur += (bytes + 255) & ~(size_t)255;
        return r;
    };
    const size_t BH = (size_t)BDIM * HDIM;
    bf16*  gxb   = (bf16*)alloc((size_t)BDIM * 1536 * 2);
    bf16*  xb    = (bf16*)alloc(BH * 2);
    bf16*  hs    = (bf16*)alloc(BH * LDIM * 2);
    bf16*  ybuf  = (bf16*)alloc(BH * LDIM * 2);
    bf16*  Wx_t  = (bf16*)alloc((size_t)1536 * 512 * 2);
    bf16*  WA    = (bf16*)alloc((size_t)524288 * 2);
    bf16*  WN    = (bf16*)alloc((size_t)262144 * 2);
    bf16*  Wc_t  = (bf16*)alloc((size_t)1048576 * 2);
    bf16*  Wh_t  = (bf16*)alloc((size_t)64 * 512 * 2);
    float* lpsum = (float*)alloc((size_t)BDIM * LDIM * 4);

    k_prep_xb<<<4096, 256, 0, stream>>>(x, xb);
    dim3 tg(16, 16);
    k_transpose_512<<<tg, 256, 0, stream>>>(Wr, Wx_t);         // x-half of Wr
    k_transpose_512<<<tg, 256, 0, stream>>>(Wz, Wx_t + 262144);
    k_transpose_512<<<tg, 256, 0, stream>>>(Wn, Wx_t + 524288);
    k_swzA<<<2048, 256, 0, stream>>>(Wr, Wz, WA);
    k_swzN<<<1024, 256, 0, stream>>>(Wn, WN);
    k_prep_wc<<<4096, 256, 0, stream>>>(w1, w3, w5, w7, Wc_t);
    k_prep_wh<<<128, 256, 0, stream>>>(Wmu, Wstd, Wh_t);

    k_gx<<<dim3(16, 12), 256, 0, stream>>>(xb, Wx_t, br, bz, bn, gxb);

    k_gru6<<<128, 1024, 0, stream>>>(WA, WN, gxb, hs);

    k_conv<<<dim3(16, 4, 20), 256, 0, stream>>>(hs, Wc_t, b1, b3, b5, b7, pa, ybuf);

    float* out_comm = (float*)d_out;
    float* out_lp   = (float*)d_out + (size_t)BDIM * LDIM * CDIM;
    k_head2<<<320, 256, 0, stream>>>(ybuf, Wh_t, bmu, bstd, eps, out_comm, lpsum);
    k_final<<<8, 256, 0, stream>>>(lpsum, out_lp);
}